// Round 10
// baseline (830.000 us; speedup 1.0000x reference)
//
#include <hip/hip_runtime.h>
#include <hip/hip_bf16.h>
#include <hip/hip_cooperative_groups.h>

#define HID 128

namespace cg = cooperative_groups;

typedef short bf16x8 __attribute__((ext_vector_type(8)));
typedef float f32x4  __attribute__((ext_vector_type(4)));
typedef unsigned short u16;
typedef unsigned long long u64;

__device__ __forceinline__ u16 f2bf(float f) {
    __hip_bfloat16 h = __float2bfloat16(f);
    return *reinterpret_cast<u16*>(&h);
}
__device__ __forceinline__ float bf2f(u16 x) {
    unsigned u = ((unsigned)x) << 16;
    return __uint_as_float(u);
}
// record: dst(17b)<<31 | src(16b)<<15 | wq(15b); low 31 bits = final s_ew record
__device__ __forceinline__ u64 pack_rec(int dst, int src, float w) {
    int wq = (int)fmaf(w, 32768.f, 0.5f);
    wq = wq > 32767 ? 32767 : wq;
    return ((u64)(unsigned)dst << 31) | ((unsigned)src << 15) | (unsigned)wq;
}

// Wt layout (u16): [0,32768) Wds^T; [32768,65536) W1^T; [65536,81920) W2^T
// W1f: folded W1^T (k<128 = (W1a+Wd@W1b)^T, k>=128 = W1b^T). bprime = b1 + bm@W1b.

struct Params {
    const float *z, *ew, *Wm, *bm, *W1, *b1, *W2, *b2;
    const int *esrc, *edst;
    float *out;
    u16 *Ab, *Pb, *Wt, *W1f;
    float *bprime;
    int *offsets, *bhist, *brun;
    unsigned *s_ew;
    u64 *tmp;
    int N, E, Mp, nbk, nP, bz8, bw, nsc, nAgg, nHO;
};

// ==================== FUSED cooperative kernel (single dispatch) ====================
__global__ __launch_bounds__(256, 4)
void fused_all(Params p)
{
    cg::grid_group grid = cg::this_grid();
    const int t = threadIdx.x;
    const int G = gridDim.x;
    __shared__ char sraw[64 * 264 * 2];   // 33.8 KB: max over phase needs

    // ---- P0: zero bhist (256) + brun (256), contiguous ----
    for (int i = blockIdx.x * 256 + t; i < 512; i += G * 256) p.bhist[i] = 0;
    __threadfence();
    grid.sync();

    // ---- P1: coarse histogram ----
    {
        int* lh = (int*)sraw;
        for (int item = blockIdx.x; item < p.nsc; item += G) {
            __syncthreads();
            lh[t] = 0;
            __syncthreads();
            const int e0 = item * 4096;
            const int eend = min(e0 + 4096, p.E);
            for (int e = e0 + t; e < eend; e += 256)
                atomicAdd(&lh[p.edst[e] >> 8], 1);
            __syncthreads();
            if (t < p.nbk && lh[t] > 0) atomicAdd(&p.bhist[t], lh[t]);
        }
    }
    __threadfence();
    grid.sync();

    // ---- P2: z-cast || w-cast || bucket scatter ----
    {
        int* cnt   = (int*)sraw;
        int* rbase = cnt + 256;
        int* bbase = rbase + 256;
        int* ps    = bbase + 256;
        const int nIt = p.bz8 + p.bw + p.nsc;
        for (int b = blockIdx.x; b < nIt; b += G) {
            if (b < p.bz8) {
                const int idx8 = (b * 256 + t) * 8;
                const int row = idx8 >> 7, col = idx8 & 127;
                bf16x8 u;
                if (row < p.N) {
                    const float4 v0 = *(const float4*)&p.z[(size_t)row * 128 + col];
                    const float4 v1 = *(const float4*)&p.z[(size_t)row * 128 + col + 4];
                    u[0] = (short)f2bf(v0.x); u[1] = (short)f2bf(v0.y);
                    u[2] = (short)f2bf(v0.z); u[3] = (short)f2bf(v0.w);
                    u[4] = (short)f2bf(v1.x); u[5] = (short)f2bf(v1.y);
                    u[6] = (short)f2bf(v1.z); u[7] = (short)f2bf(v1.w);
                } else { u = bf16x8{0,0,0,0,0,0,0,0}; }
                *(bf16x8*)&p.Ab[(size_t)row * 256 + col] = u;
            } else if (b < p.bz8 + p.bw) {
                const int idx = (b - p.bz8) * 256 + t;
                float v;
                if (idx < 32768) {
                    const int nn = idx >> 7, k = idx & 127;
                    v = (nn < 128) ? p.Wm[k * 128 + nn] : p.Wm[(128 + k) * 128 + (nn - 128)];
                } else if (idx < 65536) {
                    const int j = idx - 32768, n = j >> 8, k = j & 255;
                    v = p.W1[k * 128 + n];
                } else {
                    const int j = idx - 65536, n = j >> 7, k = j & 127;
                    v = p.W2[k * 128 + n];
                }
                p.Wt[idx] = f2bf(v);
            } else {
                __syncthreads();   // protect shared reuse across items
                const int e0 = (b - p.bz8 - p.bw) * 4096;
                const int eend = min(e0 + 4096, p.E);

                const int h = (t < p.nbk) ? p.bhist[t] : 0;
                ps[t] = h;
                __syncthreads();
                for (int off = 1; off < 256; off <<= 1) {
                    int add = (t >= off) ? ps[t - off] : 0;
                    __syncthreads();
                    ps[t] += add;
                    __syncthreads();
                }
                bbase[t] = ps[t] - h;
                cnt[t] = 0;
                __syncthreads();

                if (eend - e0 == 4096) {
                    int myb[16]; u64 myrec[16];
#pragma unroll
                    for (int i = 0; i < 16; i++) {
                        const int e = e0 + t + i * 256;
                        const int d = p.edst[e];
                        myb[i] = d >> 8;
                        myrec[i] = pack_rec(d, p.esrc[e], p.ew[e]);
                        atomicAdd(&cnt[myb[i]], 1);
                    }
                    __syncthreads();
                    if (t < p.nbk && cnt[t] > 0)
                        rbase[t] = bbase[t] + atomicAdd(&p.brun[t], cnt[t]);
                    __syncthreads();
                    cnt[t] = 0;
                    __syncthreads();
#pragma unroll
                    for (int i = 0; i < 16; i++) {
                        const int r = atomicAdd(&cnt[myb[i]], 1);
                        p.tmp[(size_t)rbase[myb[i]] + r] = myrec[i];
                    }
                } else {
                    for (int e = e0 + t; e < eend; e += 256)
                        atomicAdd(&cnt[p.edst[e] >> 8], 1);
                    __syncthreads();
                    if (t < p.nbk && cnt[t] > 0)
                        rbase[t] = bbase[t] + atomicAdd(&p.brun[t], cnt[t]);
                    __syncthreads();
                    cnt[t] = 0;
                    __syncthreads();
                    for (int e = e0 + t; e < eend; e += 256) {
                        const int d = p.edst[e];
                        const int bk = d >> 8;
                        const int r = atomicAdd(&cnt[bk], 1);
                        p.tmp[(size_t)rbase[bk] + r] = pack_rec(d, p.esrc[e], p.ew[e]);
                    }
                }
            }
        }
    }
    __threadfence();
    grid.sync();

    // ---- P3: bucket_sort || gemm_P || W'-fold ----
    {
        const int nIt = p.nbk + p.nP + 1;
        for (int b = blockIdx.x; b < nIt; b += G) {
            if (b < p.nbk) {
                __syncthreads();
                int* cnt = (int*)sraw;
                int* cur = cnt + 256;
                int* ps  = cur + 256;
                const int n0 = b << 8;
                const int nhi = min(256, p.N - n0);

                const int h = (t < p.nbk) ? p.bhist[t] : 0;
                ps[t] = h;
                __syncthreads();
                for (int off = 1; off < 256; off <<= 1) {
                    int add = (t >= off) ? ps[t - off] : 0;
                    __syncthreads();
                    ps[t] += add;
                    __syncthreads();
                }
                const int base = (b > 0) ? ps[b - 1] : 0;
                const int endp = ps[b];
                cnt[t] = 0;
                __syncthreads();

                for (int r = base + t; r < endp; r += 256)
                    atomicAdd(&cnt[(int)(p.tmp[r] >> 31) - n0], 1);
                __syncthreads();

                const int v = cnt[t];
                ps[t] = v;
                __syncthreads();
                for (int off = 1; off < 256; off <<= 1) {
                    int add = (t >= off) ? ps[t - off] : 0;
                    __syncthreads();
                    ps[t] += add;
                    __syncthreads();
                }
                cur[t] = base + ps[t] - v;
                __syncthreads();

                if (t < nhi) p.offsets[n0 + t] = cur[t];
                if (t == 0 && n0 + nhi == p.N) p.offsets[p.N] = p.E;

                for (int r = base + t; r < endp; r += 256) {
                    const u64 rec = p.tmp[r];
                    const int local = (int)(rec >> 31) - n0;
                    const int pos = atomicAdd(&cur[local], 1);
                    p.s_ew[pos] = (unsigned)(rec & 0x7FFFFFFFu);
                }
            } else if (b < p.nbk + p.nP) {
                __syncthreads();
                u16* As = (u16*)sraw;   // 64 x 136
                const int row0 = (b - p.nbk) * 64;
                const int wv = t >> 6, lane = t & 63;
                const int wy = wv & 1, wx = wv >> 1;
                const int q = lane >> 4, n = lane & 15;

#pragma unroll
                for (int i = 0; i < 4; i++) {
                    const int chunk = i * 256 + t;
                    const int row = chunk >> 4;
                    const int c8 = chunk & 15;
                    *(bf16x8*)&As[row * 136 + c8 * 8] =
                        *(const bf16x8*)&p.Ab[(size_t)(row0 + row) * 256 + c8 * 8];
                }
                __syncthreads();

                const u16* pAl = As + (wy * 32 + n) * 136 + q * 8;
                const u16* pB = p.Wt + (size_t)(128 + wx * 64 + n) * 128 + q * 8;

                f32x4 acc[2][4];
#pragma unroll
                for (int i = 0; i < 2; i++)
#pragma unroll
                    for (int j = 0; j < 4; j++) acc[i][j] = f32x4{0.f, 0.f, 0.f, 0.f};

#pragma unroll
                for (int kk = 0; kk < 128; kk += 32) {
                    bf16x8 a0 = *(const bf16x8*)(pAl + kk);
                    bf16x8 a1 = *(const bf16x8*)(pAl + 16 * 136 + kk);
                    bf16x8 bfr[4];
#pragma unroll
                    for (int ni = 0; ni < 4; ni++)
                        bfr[ni] = *(const bf16x8*)(pB + (size_t)ni * 16 * 128 + kk);
#pragma unroll
                    for (int ni = 0; ni < 4; ni++) {
                        acc[0][ni] = __builtin_amdgcn_mfma_f32_16x16x32_bf16(a0, bfr[ni], acc[0][ni], 0, 0, 0);
                        acc[1][ni] = __builtin_amdgcn_mfma_f32_16x16x32_bf16(a1, bfr[ni], acc[1][ni], 0, 0, 0);
                    }
                }

#pragma unroll
                for (int mi = 0; mi < 2; mi++) {
#pragma unroll
                    for (int ni = 0; ni < 4; ni++) {
                        const int rbase2 = row0 + wy * 32 + mi * 16 + q * 4;
                        const int c = wx * 64 + ni * 16 + n;
#pragma unroll
                        for (int r = 0; r < 4; r++)
                            p.Pb[(size_t)(rbase2 + r) * 128 + c] = f2bf(acc[mi][ni][r]);
                    }
                }
            } else {
                // W'-fold (one item)
                const u16* W1t = p.Wt + 32768;
                const int wv = t >> 6, lane = t & 63;
                const int q = lane >> 4, n16 = lane & 15;

#pragma unroll
                for (int i = 0; i < 8; i++) {
                    const int idx8 = (i * 256 + t) * 8;
                    const int row = idx8 >> 7, c = idx8 & 127;
                    *(bf16x8*)&p.W1f[row * 256 + 128 + c] =
                        *(const bf16x8*)&W1t[row * 256 + 128 + c];
                }

                const int r0 = wv * 32;
                const u16* pA = W1t + (size_t)(r0 + n16) * 256 + 128 + q * 8;

                f32x4 acc[2][8];
#pragma unroll
                for (int i = 0; i < 2; i++)
#pragma unroll
                    for (int j = 0; j < 8; j++) acc[i][j] = f32x4{0.f, 0.f, 0.f, 0.f};

#pragma unroll
                for (int kk = 0; kk < 128; kk += 32) {
                    bf16x8 a0 = *(const bf16x8*)(pA + kk);
                    bf16x8 a1 = *(const bf16x8*)(pA + 16 * 256 + kk);
                    bf16x8 bfr[8];
#pragma unroll
                    for (int ni = 0; ni < 8; ni++) {
                        const float* src = &p.Wm[(size_t)(ni * 16 + n16) * 128 + kk + q * 8];
                        const float4 v0 = *(const float4*)src;
                        const float4 v1 = *(const float4*)(src + 4);
                        bf16x8 bb;
                        bb[0] = (short)f2bf(v0.x); bb[1] = (short)f2bf(v0.y);
                        bb[2] = (short)f2bf(v0.z); bb[3] = (short)f2bf(v0.w);
                        bb[4] = (short)f2bf(v1.x); bb[5] = (short)f2bf(v1.y);
                        bb[6] = (short)f2bf(v1.z); bb[7] = (short)f2bf(v1.w);
                        bfr[ni] = bb;
                    }
#pragma unroll
                    for (int ni = 0; ni < 8; ni++) {
                        acc[0][ni] = __builtin_amdgcn_mfma_f32_16x16x32_bf16(a0, bfr[ni], acc[0][ni], 0, 0, 0);
                        acc[1][ni] = __builtin_amdgcn_mfma_f32_16x16x32_bf16(a1, bfr[ni], acc[1][ni], 0, 0, 0);
                    }
                }

#pragma unroll
                for (int mi = 0; mi < 2; mi++) {
#pragma unroll
                    for (int ni = 0; ni < 8; ni++) {
                        const int row = r0 + mi * 16 + q * 4;
                        const int c = ni * 16 + n16;
#pragma unroll
                        for (int r = 0; r < 4; r++) {
                            const int rr = row + r;
                            p.W1f[rr * 256 + c] =
                                f2bf(acc[mi][ni][r] + bf2f(W1t[rr * 256 + c]));
                        }
                    }
                }

                if (t < 128) {
                    float s = p.b1[t];
                    for (int c = 0; c < 128; c++)
                        s = fmaf(p.bm[c], bf2f(W1t[t * 256 + 128 + c]), s);
                    p.bprime[t] = s;
                }
            }
        }
    }
    __threadfence();
    grid.sync();

    // ---- P4: aggregate (group-per-node) ----
    {
        const float* ww = p.Wm + 256 * 128;
        const int lane = t & 63;
        const int c0 = (lane & 15) * 8;
        for (int item = blockIdx.x; item < p.nAgg; item += G) {
            const int nd = item * 16 + ((t >> 6) << 2) + (lane >> 4);
            if (nd >= p.Mp) continue;
            u16* dst = &p.Ab[(size_t)nd * 256 + 128 + c0];

            if (nd >= p.N) {
                bf16x8 zv = {0, 0, 0, 0, 0, 0, 0, 0};
                *(bf16x8*)dst = zv;
                continue;
            }
            const int start = p.offsets[nd];
            const int end   = p.offsets[nd + 1];

            if (end <= start) {
                float acc8[8];
#pragma unroll
                for (int j = 0; j < 8; j++) acc8[j] = 0.f;
                for (int k = 0; k < 128; k++) {
                    const float zk = bf2f(p.Ab[(size_t)nd * 256 + k]);
#pragma unroll
                    for (int j = 0; j < 8; j++)
                        acc8[j] = fmaf(zk, bf2f(p.Wt[(size_t)(c0 + j) * 128 + k]), acc8[j]);
                }
                bf16x8 outv;
#pragma unroll
                for (int j = 0; j < 8; j++)
                    outv[j] = (short)f2bf(-(acc8[j] + p.bm[c0 + j]));
                *(bf16x8*)dst = outv;
                continue;
            }

            float wwv[8];
            {
                const float4 wa = *(const float4*)&ww[c0];
                const float4 wb = *(const float4*)&ww[c0 + 4];
                wwv[0] = wa.x; wwv[1] = wa.y; wwv[2] = wa.z; wwv[3] = wa.w;
                wwv[4] = wb.x; wwv[5] = wb.y; wwv[6] = wb.z; wwv[7] = wb.w;
            }
            const float kq = 1.f / 32768.f;
            float m[8];
#pragma unroll
            for (int j = 0; j < 8; j++) m[j] = -INFINITY;

            const int last = end - 1;
            for (int eb = start; eb < end; eb += 8) {
                unsigned u[8];
#pragma unroll
                for (int i = 0; i < 8; i++) {
                    int e = eb + i; if (e > last) e = last;
                    u[i] = p.s_ew[e];
                }
                bf16x8 pp[8];
#pragma unroll
                for (int i = 0; i < 8; i++)
                    pp[i] = *(const bf16x8*)&p.Pb[(size_t)(u[i] >> 15) * 128 + c0];
#pragma unroll
                for (int i = 0; i < 8; i++) {
                    const float w = (float)(u[i] & 32767u) * kq;
#pragma unroll
                    for (int j = 0; j < 8; j++)
                        m[j] = fmaxf(m[j], fmaf(w, wwv[j], bf2f((u16)pp[i][j])));
                }
            }

            bf16x8 outv;
#pragma unroll
            for (int j = 0; j < 8; j++)
                outv[j] = (short)f2bf(m[j]);
            *(bf16x8*)dst = outv;
        }
    }
    __threadfence();
    grid.sync();

    // ---- P5: gemm_HO (64-row tile; 33.8 KB LDS keeps 4 blocks/CU co-resident) ----
    {
        u16* smem = (u16*)sraw;
        const u16* W1t = p.W1f;
        const u16* W2t = p.Wt + 65536;
        const int wv = t >> 6, lane = t & 63;
        const int wy = wv & 1, wx = wv >> 1;
        const int q = lane >> 4, n = lane & 15;

        for (int item = blockIdx.x; item < p.nHO; item += G) {
            __syncthreads();
            const int row0 = item * 64;

#pragma unroll
            for (int i = 0; i < 8; i++) {
                const int chunk = i * 256 + t;
                const int row = chunk >> 5;
                const int c8 = chunk & 31;
                *(bf16x8*)&smem[row * 264 + c8 * 8] =
                    *(const bf16x8*)&p.Ab[(size_t)(row0 + row) * 256 + c8 * 8];
            }
            __syncthreads();

            f32x4 acc[2][4];
            {
                const u16* pAl = smem + (wy * 32 + n) * 264 + q * 8;
                const u16* pB = W1t + (size_t)(wx * 64 + n) * 256 + q * 8;
#pragma unroll
                for (int i = 0; i < 2; i++)
#pragma unroll
                    for (int j = 0; j < 4; j++) acc[i][j] = f32x4{0.f, 0.f, 0.f, 0.f};
#pragma unroll
                for (int kk = 0; kk < 256; kk += 32) {
                    bf16x8 b0 = *(const bf16x8*)(pB + kk);
                    bf16x8 b1f = *(const bf16x8*)(pB + 16 * 256 + kk);
                    bf16x8 b2f = *(const bf16x8*)(pB + 32 * 256 + kk);
                    bf16x8 b3f = *(const bf16x8*)(pB + 48 * 256 + kk);
                    bf16x8 a0 = *(const bf16x8*)(pAl + kk);
                    bf16x8 a1 = *(const bf16x8*)(pAl + 16 * 264 + kk);
                    acc[0][0] = __builtin_amdgcn_mfma_f32_16x16x32_bf16(a0, b0,  acc[0][0], 0, 0, 0);
                    acc[0][1] = __builtin_amdgcn_mfma_f32_16x16x32_bf16(a0, b1f, acc[0][1], 0, 0, 0);
                    acc[0][2] = __builtin_amdgcn_mfma_f32_16x16x32_bf16(a0, b2f, acc[0][2], 0, 0, 0);
                    acc[0][3] = __builtin_amdgcn_mfma_f32_16x16x32_bf16(a0, b3f, acc[0][3], 0, 0, 0);
                    acc[1][0] = __builtin_amdgcn_mfma_f32_16x16x32_bf16(a1, b0,  acc[1][0], 0, 0, 0);
                    acc[1][1] = __builtin_amdgcn_mfma_f32_16x16x32_bf16(a1, b1f, acc[1][1], 0, 0, 0);
                    acc[1][2] = __builtin_amdgcn_mfma_f32_16x16x32_bf16(a1, b2f, acc[1][2], 0, 0, 0);
                    acc[1][3] = __builtin_amdgcn_mfma_f32_16x16x32_bf16(a1, b3f, acc[1][3], 0, 0, 0);
                }
            }
            __syncthreads();

#pragma unroll
            for (int mi = 0; mi < 2; mi++) {
#pragma unroll
                for (int ni = 0; ni < 4; ni++) {
                    const int rl = wy * 32 + mi * 16 + q * 4;
                    const int c = wx * 64 + ni * 16 + n;
#pragma unroll
                    for (int r = 0; r < 4; r++) {
                        float v = acc[mi][ni][r] + p.bprime[c];
                        smem[(rl + r) * 136 + c] = f2bf(fmaxf(v, 0.f));
                    }
                }
            }
            __syncthreads();

            {
                const u16* pB = W2t + (size_t)(wx * 64 + n) * 128 + q * 8;
                const u16* pHl = smem + (wy * 32 + n) * 136 + q * 8;
#pragma unroll
                for (int i = 0; i < 2; i++)
#pragma unroll
                    for (int j = 0; j < 4; j++) acc[i][j] = f32x4{0.f, 0.f, 0.f, 0.f};
#pragma unroll
                for (int kk = 0; kk < 128; kk += 32) {
                    bf16x8 b0 = *(const bf16x8*)(pB + kk);
                    bf16x8 b1f = *(const bf16x8*)(pB + 16 * 128 + kk);
                    bf16x8 b2f = *(const bf16x8*)(pB + 32 * 128 + kk);
                    bf16x8 b3f = *(const bf16x8*)(pB + 48 * 128 + kk);
                    bf16x8 a0 = *(const bf16x8*)(pHl + kk);
                    bf16x8 a1 = *(const bf16x8*)(pHl + 16 * 136 + kk);
                    acc[0][0] = __builtin_amdgcn_mfma_f32_16x16x32_bf16(a0, b0,  acc[0][0], 0, 0, 0);
                    acc[0][1] = __builtin_amdgcn_mfma_f32_16x16x32_bf16(a0, b1f, acc[0][1], 0, 0, 0);
                    acc[0][2] = __builtin_amdgcn_mfma_f32_16x16x32_bf16(a0, b2f, acc[0][2], 0, 0, 0);
                    acc[0][3] = __builtin_amdgcn_mfma_f32_16x16x32_bf16(a0, b3f, acc[0][3], 0, 0, 0);
                    acc[1][0] = __builtin_amdgcn_mfma_f32_16x16x32_bf16(a1, b0,  acc[1][0], 0, 0, 0);
                    acc[1][1] = __builtin_amdgcn_mfma_f32_16x16x32_bf16(a1, b1f, acc[1][1], 0, 0, 0);
                    acc[1][2] = __builtin_amdgcn_mfma_f32_16x16x32_bf16(a1, b2f, acc[1][2], 0, 0, 0);
                    acc[1][3] = __builtin_amdgcn_mfma_f32_16x16x32_bf16(a1, b3f, acc[1][3], 0, 0, 0);
                }

#pragma unroll
                for (int mi = 0; mi < 2; mi++) {
#pragma unroll
                    for (int ni = 0; ni < 4; ni++) {
                        const int rbase = row0 + wy * 32 + mi * 16 + q * 4;
                        const int c = wx * 64 + ni * 16 + n;
#pragma unroll
                        for (int r = 0; r < 4; r++) {
                            const int rr = rbase + r;
                            if (rr >= p.N) continue;
                            p.out[(size_t)rr * 128 + c] = acc[mi][ni][r] + p.b2[c];
                        }
                    }
                }
            }
        }
    }
}

// ==================== Standalone fallback kernels (R9 path) ====================
__global__ __launch_bounds__(256)
void hist_kernel(const int* __restrict__ edst, int* __restrict__ bhist,
                 int E, int nbk)
{
    __shared__ int lh[256];
    const int b = blockIdx.x;
    const int t = threadIdx.x;
    lh[t] = 0;
    __syncthreads();
    const int e0 = b * 4096;
    const int eend = min(e0 + 4096, E);
    for (int e = e0 + t; e < eend; e += 256)
        atomicAdd(&lh[edst[e] >> 8], 1);
    __syncthreads();
    if (t < nbk && lh[t] > 0) atomicAdd(&bhist[t], lh[t]);
}

__global__ __launch_bounds__(256)
void cast_scatter(const float* __restrict__ z, const float* __restrict__ Wm,
                  const float* __restrict__ W1, const float* __restrict__ W2,
                  const int* __restrict__ esrc, const int* __restrict__ edst,
                  const float* __restrict__ ew,
                  const int* __restrict__ bhist, int* __restrict__ brun,
                  u16* __restrict__ Ab, u16* __restrict__ Wt, u64* __restrict__ tmp,
                  int N, int Mp, int E, int bz, int bw, int nbk)
{
    const int b = blockIdx.x;
    const int t = threadIdx.x;
    if (b < bz) {
        const int idx8 = (b * 256 + t) * 8;
        const int row = idx8 >> 7, col = idx8 & 127;
        bf16x8 u;
        if (row < N) {
            const float4 v0 = *(const float4*)&z[(size_t)row * 128 + col];
            const float4 v1 = *(const float4*)&z[(size_t)row * 128 + col + 4];
            u[0] = (short)f2bf(v0.x); u[1] = (short)f2bf(v0.y);
            u[2] = (short)f2bf(v0.z); u[3] = (short)f2bf(v0.w);
            u[4] = (short)f2bf(v1.x); u[5] = (short)f2bf(v1.y);
            u[6] = (short)f2bf(v1.z); u[7] = (short)f2bf(v1.w);
        } else { u = bf16x8{0,0,0,0,0,0,0,0}; }
        *(bf16x8*)&Ab[(size_t)row * 256 + col] = u;
    } else if (b < bz + bw) {
        const int idx = (b - bz) * 256 + t;
        float v;
        if (idx < 32768) {
            const int nn = idx >> 7, k = idx & 127;
            v = (nn < 128) ? Wm[k * 128 + nn] : Wm[(128 + k) * 128 + (nn - 128)];
        } else if (idx < 65536) {
            const int j = idx - 32768, n = j >> 8, k = j & 255;
            v = W1[k * 128 + n];
        } else {
            const int j = idx - 65536, n = j >> 7, k = j & 127;
            v = W2[k * 128 + n];
        }
        Wt[idx] = f2bf(v);
    } else {
        __shared__ int cnt[256];
        __shared__ int rbase[256];
        __shared__ int bbase[256];
        __shared__ int ps[256];
        const int e0 = (b - bz - bw) * 4096;
        const int eend = min(e0 + 4096, E);

        const int h = (t < nbk) ? bhist[t] : 0;
        ps[t] = h;
        __syncthreads();
        for (int off = 1; off < 256; off <<= 1) {
            int add = (t >= off) ? ps[t - off] : 0;
            __syncthreads();
            ps[t] += add;
            __syncthreads();
        }
        bbase[t] = ps[t] - h;
        cnt[t] = 0;
        __syncthreads();

        if (eend - e0 == 4096) {
            int myb[16]; u64 myrec[16];
#pragma unroll
            for (int i = 0; i < 16; i++) {
                const int e = e0 + t + i * 256;
                const int d = edst[e];
                myb[i] = d >> 8;
                myrec[i] = pack_rec(d, esrc[e], ew[e]);
                atomicAdd(&cnt[myb[i]], 1);
            }
            __syncthreads();
            if (t < nbk && cnt[t] > 0) rbase[t] = bbase[t] + atomicAdd(&brun[t], cnt[t]);
            __syncthreads();
            cnt[t] = 0;
            __syncthreads();
#pragma unroll
            for (int i = 0; i < 16; i++) {
                const int r = atomicAdd(&cnt[myb[i]], 1);
                tmp[(size_t)rbase[myb[i]] + r] = myrec[i];
            }
        } else {
            for (int e = e0 + t; e < eend; e += 256)
                atomicAdd(&cnt[edst[e] >> 8], 1);
            __syncthreads();
            if (t < nbk && cnt[t] > 0) rbase[t] = bbase[t] + atomicAdd(&brun[t], cnt[t]);
            __syncthreads();
            cnt[t] = 0;
            __syncthreads();
            for (int e = e0 + t; e < eend; e += 256) {
                const int d = edst[e];
                const int bk = d >> 8;
                const int r = atomicAdd(&cnt[bk], 1);
                tmp[(size_t)rbase[bk] + r] = pack_rec(d, esrc[e], ew[e]);
            }
        }
    }
}

__global__ __launch_bounds__(256)
void sort_gemmP(const u64* __restrict__ tmp, const int* __restrict__ bhist,
                int* __restrict__ offsets, unsigned* __restrict__ s_ew,
                int N, int E, int nbk,
                const u16* __restrict__ Ab, const u16* __restrict__ Wt,
                u16* __restrict__ Pb, int Mp, int nP,
                const float* __restrict__ Wm, const float* __restrict__ b1,
                const float* __restrict__ bm,
                u16* __restrict__ W1f, float* __restrict__ bprime)
{
    const int t = threadIdx.x;

    if (blockIdx.x < (unsigned)nbk) {
        __shared__ int cnt[256];
        __shared__ int cur[256];
        __shared__ int ps[256];
        const int b = blockIdx.x;
        const int n0 = b << 8;
        const int nhi = min(256, N - n0);

        const int h = (t < nbk) ? bhist[t] : 0;
        ps[t] = h;
        __syncthreads();
        for (int off = 1; off < 256; off <<= 1) {
            int add = (t >= off) ? ps[t - off] : 0;
            __syncthreads();
            ps[t] += add;
            __syncthreads();
        }
        const int base = (b > 0) ? ps[b - 1] : 0;
        const int endp = ps[b];
        cnt[t] = 0;
        __syncthreads();

        for (int r = base + t; r < endp; r += 256)
            atomicAdd(&cnt[(int)(tmp[r] >> 31) - n0], 1);
        __syncthreads();

        const int v = cnt[t];
        ps[t] = v;
        __syncthreads();
        for (int off = 1; off < 256; off <<= 1) {
            int add = (t >= off) ? ps[t - off] : 0;
            __syncthreads();
            ps[t] += add;
            __syncthreads();
        }
        cur[t] = base + ps[t] - v;
        __syncthreads();

        if (t < nhi) offsets[n0 + t] = cur[t];
        if (t == 0 && n0 + nhi == N) offsets[N] = E;

        for (int r = base + t; r < endp; r += 256) {
            const u64 rec = tmp[r];
            const int local = (int)(rec >> 31) - n0;
            const int pos = atomicAdd(&cur[local], 1);
            s_ew[pos] = (unsigned)(rec & 0x7FFFFFFFu);
        }
    } else if (blockIdx.x < (unsigned)(nbk + nP)) {
        __shared__ u16 As[64 * 136];
        const int row0 = (blockIdx.x - nbk) * 64;
        const int wv = t >> 6, lane = t & 63;
        const int wy = wv & 1, wx = wv >> 1;
        const int q = lane >> 4, n = lane & 15;

#pragma unroll
        for (int i = 0; i < 4; i++) {
            const int chunk = i * 256 + t;
            const int row = chunk >> 4;
            const int c8 = chunk & 15;
            *(bf16x8*)&As[row * 136 + c8 * 8] =
                *(const bf16x8*)&Ab[(size_t)(row0 + row) * 256 + c8 * 8];
        }
        __syncthreads();

        const u16* pAl = As + (wy * 32 + n) * 136 + q * 8;
        const u16* pB = Wt + (size_t)(128 + wx * 64 + n) * 128 + q * 8;

        f32x4 acc[2][4];
#pragma unroll
        for (int i = 0; i < 2; i++)
#pragma unroll
            for (int j = 0; j < 4; j++) acc[i][j] = f32x4{0.f, 0.f, 0.f, 0.f};

#pragma unroll
        for (int kk = 0; kk < 128; kk += 32) {
            bf16x8 a0 = *(const bf16x8*)(pAl + kk);
            bf16x8 a1 = *(const bf16x8*)(pAl + 16 * 136 + kk);
            bf16x8 bfr[4];
#pragma unroll
            for (int ni = 0; ni < 4; ni++)
                bfr[ni] = *(const bf16x8*)(pB + (size_t)ni * 16 * 128 + kk);
#pragma unroll
            for (int ni = 0; ni < 4; ni++) {
                acc[0][ni] = __builtin_amdgcn_mfma_f32_16x16x32_bf16(a0, bfr[ni], acc[0][ni], 0, 0, 0);
                acc[1][ni] = __builtin_amdgcn_mfma_f32_16x16x32_bf16(a1, bfr[ni], acc[1][ni], 0, 0, 0);
            }
        }

#pragma unroll
        for (int mi = 0; mi < 2; mi++) {
#pragma unroll
            for (int ni = 0; ni < 4; ni++) {
                const int rbase2 = row0 + wy * 32 + mi * 16 + q * 4;
                const int c = wx * 64 + ni * 16 + n;
#pragma unroll
                for (int r = 0; r < 4; r++)
                    Pb[(size_t)(rbase2 + r) * 128 + c] = f2bf(acc[mi][ni][r]);
            }
        }
    } else {
        const u16* W1t = Wt + 32768;
        const int wv = t >> 6, lane = t & 63;
        const int q = lane >> 4, n16 = lane & 15;

#pragma unroll
        for (int i = 0; i < 8; i++) {
            const int idx8 = (i * 256 + t) * 8;
            const int row = idx8 >> 7, c = idx8 & 127;
            *(bf16x8*)&W1f[row * 256 + 128 + c] =
                *(const bf16x8*)&W1t[row * 256 + 128 + c];
        }

        const int r0 = wv * 32;
        const u16* pA = W1t + (size_t)(r0 + n16) * 256 + 128 + q * 8;

        f32x4 acc[2][8];
#pragma unroll
        for (int i = 0; i < 2; i++)
#pragma unroll
            for (int j = 0; j < 8; j++) acc[i][j] = f32x4{0.f, 0.f, 0.f, 0.f};

#pragma unroll
        for (int kk = 0; kk < 128; kk += 32) {
            bf16x8 a0 = *(const bf16x8*)(pA + kk);
            bf16x8 a1 = *(const bf16x8*)(pA + 16 * 256 + kk);
            bf16x8 bfr[8];
#pragma unroll
            for (int ni = 0; ni < 8; ni++) {
                const float* src = &Wm[(size_t)(ni * 16 + n16) * 128 + kk + q * 8];
                const float4 v0 = *(const float4*)src;
                const float4 v1 = *(const float4*)(src + 4);
                bf16x8 bb;
                bb[0] = (short)f2bf(v0.x); bb[1] = (short)f2bf(v0.y);
                bb[2] = (short)f2bf(v0.z); bb[3] = (short)f2bf(v0.w);
                bb[4] = (short)f2bf(v1.x); bb[5] = (short)f2bf(v1.y);
                bb[6] = (short)f2bf(v1.z); bb[7] = (short)f2bf(v1.w);
                bfr[ni] = bb;
            }
#pragma unroll
            for (int ni = 0; ni < 8; ni++) {
                acc[0][ni] = __builtin_amdgcn_mfma_f32_16x16x32_bf16(a0, bfr[ni], acc[0][ni], 0, 0, 0);
                acc[1][ni] = __builtin_amdgcn_mfma_f32_16x16x32_bf16(a1, bfr[ni], acc[1][ni], 0, 0, 0);
            }
        }

#pragma unroll
        for (int mi = 0; mi < 2; mi++) {
#pragma unroll
            for (int ni = 0; ni < 8; ni++) {
                const int row = r0 + mi * 16 + q * 4;
                const int c = ni * 16 + n16;
#pragma unroll
                for (int r = 0; r < 4; r++) {
                    const int rr = row + r;
                    W1f[rr * 256 + c] =
                        f2bf(acc[mi][ni][r] + bf2f(W1t[rr * 256 + c]));
                }
            }
        }

        if (t < 128) {
            float s = b1[t];
            for (int c = 0; c < 128; c++)
                s = fmaf(bm[c], bf2f(W1t[t * 256 + 128 + c]), s);
            bprime[t] = s;
        }
    }
}

__global__ __launch_bounds__(256)
void aggregate_kernel(const u16* __restrict__ Pb,
                      const float* __restrict__ bm,
                      const float* __restrict__ ww,
                      const int* __restrict__ offsets,
                      const unsigned* __restrict__ s_ew,
                      u16* __restrict__ Ab,
                      const u16* __restrict__ WdT,
                      int N, int Mp)
{
    const int t = threadIdx.x;
    const int lane = t & 63;
    const int c0 = (lane & 15) * 8;
    const int nd = blockIdx.x * 16 + ((t >> 6) << 2) + (lane >> 4);
    if (nd >= Mp) return;

    u16* dst = &Ab[(size_t)nd * 256 + 128 + c0];

    if (nd >= N) {
        bf16x8 zv = {0, 0, 0, 0, 0, 0, 0, 0};
        *(bf16x8*)dst = zv;
        return;
    }

    const int start = offsets[nd];
    const int end   = offsets[nd + 1];

    if (end <= start) {
        float acc8[8];
#pragma unroll
        for (int j = 0; j < 8; j++) acc8[j] = 0.f;
        for (int k = 0; k < 128; k++) {
            const float zk = bf2f(Ab[(size_t)nd * 256 + k]);
#pragma unroll
            for (int j = 0; j < 8; j++)
                acc8[j] = fmaf(zk, bf2f(WdT[(size_t)(c0 + j) * 128 + k]), acc8[j]);
        }
        bf16x8 outv;
#pragma unroll
        for (int j = 0; j < 8; j++)
            outv[j] = (short)f2bf(-(acc8[j] + bm[c0 + j]));
        *(bf16x8*)dst = outv;
        return;
    }

    float wwv[8];
    {
        const float4 wa = *(const float4*)&ww[c0];
        const float4 wb = *(const float4*)&ww[c0 + 4];
        wwv[0] = wa.x; wwv[1] = wa.y; wwv[2] = wa.z; wwv[3] = wa.w;
        wwv[4] = wb.x; wwv[5] = wb.y; wwv[6] = wb.z; wwv[7] = wb.w;
    }

    const float kq = 1.f / 32768.f;
    float m[8];
#pragma unroll
    for (int j = 0; j < 8; j++) m[j] = -INFINITY;

    const int last = end - 1;
    for (int eb = start; eb < end; eb += 8) {
        unsigned u[8];
#pragma unroll
        for (int i = 0; i < 8; i++) {
            int e = eb + i; if (e > last) e = last;
            u[i] = s_ew[e];
        }
        bf16x8 p[8];
#pragma unroll
        for (int i = 0; i < 8; i++)
            p[i] = *(const bf16x8*)&Pb[(size_t)(u[i] >> 15) * 128 + c0];
#pragma unroll
        for (int i = 0; i < 8; i++) {
            const float w = (float)(u[i] & 32767u) * kq;
#pragma unroll
            for (int j = 0; j < 8; j++)
                m[j] = fmaxf(m[j], fmaf(w, wwv[j], bf2f((u16)p[i][j])));
        }
    }

    bf16x8 outv;
#pragma unroll
    for (int j = 0; j < 8; j++)
        outv[j] = (short)f2bf(m[j]);
    *(bf16x8*)dst = outv;
}

__global__ __launch_bounds__(256)
void gemm_HO(const u16* __restrict__ Ab, const u16* __restrict__ W1t,
             const float* __restrict__ b1, const u16* __restrict__ W2t,
             const float* __restrict__ b2, float* __restrict__ out, int Mstore)
{
    __shared__ u16 smem[128 * 264];

    const int row0 = blockIdx.x * 128;
    const int tid = threadIdx.x;
    const int wv = tid >> 6, lane = tid & 63;
    const int wy = wv & 1, wx = wv >> 1;
    const int q = lane >> 4, n = lane & 15;

#pragma unroll
    for (int i = 0; i < 16; i++) {
        const int chunk = i * 256 + tid;
        const int row = chunk >> 5;
        const int c8 = chunk & 31;
        *(bf16x8*)&smem[row * 264 + c8 * 8] =
            *(const bf16x8*)&Ab[(size_t)(row0 + row) * 256 + c8 * 8];
    }
    __syncthreads();

    f32x4 acc[4][4];

    {
        const u16* pAl = smem + (wy * 64 + n) * 264 + q * 8;
        const u16* pB = W1t + (size_t)(wx * 64 + n) * 256 + q * 8;

#pragma unroll
        for (int i = 0; i < 4; i++)
#pragma unroll
            for (int j = 0; j < 4; j++) acc[i][j] = f32x4{0.f, 0.f, 0.f, 0.f};

#pragma unroll
        for (int kk = 0; kk < 256; kk += 32) {
            bf16x8 a[4], bfr[4];
#pragma unroll
            for (int mi = 0; mi < 4; mi++)
                a[mi] = *(const bf16x8*)(pAl + mi * 16 * 264 + kk);
#pragma unroll
            for (int ni = 0; ni < 4; ni++)
                bfr[ni] = *(const bf16x8*)(pB + (size_t)ni * 16 * 256 + kk);
#pragma unroll
            for (int mi = 0; mi < 4; mi++)
#pragma unroll
                for (int ni = 0; ni < 4; ni++)
                    acc[mi][ni] = __builtin_amdgcn_mfma_f32_16x16x32_bf16(a[mi], bfr[ni], acc[mi][ni], 0, 0, 0);
        }
    }
    __syncthreads();

#pragma unroll
    for (int mi = 0; mi < 4; mi++) {
#pragma unroll
        for (int ni = 0; ni < 4; ni++) {
            const int rl = wy * 64 + mi * 16 + q * 4;
            const int c = wx * 64 + ni * 16 + n;
#pragma unroll
            for (int r = 0; r < 4; r++) {
                float v = acc[mi][ni][r] + b1[c];
                smem[(rl + r) * 136 + c] = f2bf(fmaxf(v, 0.f));
            }
        }
    }
    __syncthreads();

    {
        const u16* pB = W2t + (size_t)(wx * 64 + n) * 128 + q * 8;
        const u16* pHl = smem + (wy * 64 + n) * 136 + q * 8;

#pragma unroll
        for (int i = 0; i < 4; i++)
#pragma unroll
            for (int j = 0; j < 4; j++) acc[i][j] = f32x4{0.f, 0.f, 0.f, 0.f};

#pragma unroll
        for (int kk = 0; kk < 128; kk += 32) {
            bf16x8 a[4], bfr[4];
#pragma unroll
            for (int mi = 0; mi < 4; mi++)
                a[mi] = *(const bf16x8*)(pHl + mi * 16 * 136 + kk);
#pragma unroll
            for (int ni = 0; ni < 4; ni++)
                bfr[ni] = *(const bf16x8*)(pB + (size_t)ni * 16 * 128 + kk);
#pragma unroll
            for (int mi = 0; mi < 4; mi++)
#pragma unroll
                for (int ni = 0; ni < 4; ni++)
                    acc[mi][ni] = __builtin_amdgcn_mfma_f32_16x16x32_bf16(a[mi], bfr[ni], acc[mi][ni], 0, 0, 0);
        }

#pragma unroll
        for (int mi = 0; mi < 4; mi++) {
#pragma unroll
            for (int ni = 0; ni < 4; ni++) {
                const int rbase = row0 + wy * 64 + mi * 16 + q * 4;
                const int c = wx * 64 + ni * 16 + n;
#pragma unroll
                for (int r = 0; r < 4; r++) {
                    const int rr = rbase + r;
                    if (rr >= Mstore) continue;
                    out[(size_t)rr * 128 + c] = acc[mi][ni][r] + b2[c];
                }
            }
        }
    }
}

extern "C" void kernel_launch(void* const* d_in, const int* in_sizes, int n_in,
                              void* d_out, int out_size, void* d_ws, size_t ws_size,
                              hipStream_t stream) {
    const float* z    = (const float*)d_in[0];
    const float* ew   = (const float*)d_in[1];
    const int*   esrc = (const int*)d_in[2];
    const int*   edst = (const int*)d_in[3];
    const float* Wm   = (const float*)d_in[4];
    const float* bm   = (const float*)d_in[5];
    const float* W1   = (const float*)d_in[6];
    const float* b1   = (const float*)d_in[7];
    const float* W2   = (const float*)d_in[8];
    const float* b2   = (const float*)d_in[9];
    float* out = (float*)d_out;

    const int N  = in_sizes[0] / HID;          // 50000
    const int E  = in_sizes[1];                // 800000
    const int Mp = ((N + 127) / 128) * 128;    // 50048
    const int nbk = (N + 255) / 256;           // 196
    const int nP  = Mp / 64;

    // workspace layout
    char* w = (char*)d_ws;
    u16*  Ab      = (u16*)w;      w += (size_t)Mp * 256 * 2;   // [zb | m]
    u16*  Pb      = (u16*)w;      w += (size_t)Mp * 128 * 2;   // zWs only
    u16*  Wt      = (u16*)w;      w += (size_t)81920 * 2;
    u16*  W1f     = (u16*)w;      w += (size_t)32768 * 2;
    float* bprime = (float*)w;    w += 128 * 4;
    int*  offsets = (int*)w;      w += (size_t)(N + 64) * 4;
    int*  bhist   = (int*)w;      w += 256 * 4;
    int*  brun    = (int*)w;      w += 256 * 4;
    unsigned* s_ew = (unsigned*)w; w += (size_t)E * 4;
    u64*  tmp     = (u64*)w;      w += (size_t)E * 8;

    const int bz8 = (Mp * 16 + 255) / 256;
    const int bw  = (81920 + 255) / 256;
    const int nsc = (E + 4095) / 4096;

    // ---- try the single cooperative dispatch ----
    static int s_grid = -2;   // -2 = uncomputed
    if (s_grid == -2) {
        int nBlk = 0, nCU = 0;
        hipDeviceProp_t prop;
        if (hipGetDeviceProperties(&prop, 0) == hipSuccess) nCU = prop.multiProcessorCount;
        if (hipOccupancyMaxActiveBlocksPerMultiprocessor(&nBlk, fused_all, 256, 0) != hipSuccess)
            nBlk = 0;
        s_grid = (nBlk > 0 && nCU > 0) ? nBlk * nCU : 0;
    }

    if (s_grid >= 256) {
        Params p;
        p.z = z; p.ew = ew; p.Wm = Wm; p.bm = bm; p.W1 = W1; p.b1 = b1;
        p.W2 = W2; p.b2 = b2; p.esrc = esrc; p.edst = edst; p.out = out;
        p.Ab = Ab; p.Pb = Pb; p.Wt = Wt; p.W1f = W1f; p.bprime = bprime;
        p.offsets = offsets; p.bhist = bhist; p.brun = brun;
        p.s_ew = s_ew; p.tmp = tmp;
        p.N = N; p.E = E; p.Mp = Mp; p.nbk = nbk; p.nP = nP;
        p.bz8 = bz8; p.bw = bw; p.nsc = nsc;
        p.nAgg = (Mp + 15) / 16; p.nHO = Mp / 64;

        void* args[] = { &p };
        hipError_t err = hipLaunchCooperativeKernel((const void*)fused_all,
                                                    dim3(s_grid), dim3(256),
                                                    args, 0, stream);
        if (err == hipSuccess) return;
        (void)hipGetLastError();   // clear; fall through to standalone path
        s_grid = 0;                // don't retry cooperative in later captures
    }

    // ---- fallback: proven 6-dispatch R9 path ----
    hipMemsetAsync(bhist, 0, 512 * sizeof(int), stream);
    hist_kernel<<<nsc, 256, 0, stream>>>(edst, bhist, E, nbk);
    cast_scatter<<<bz8 + bw + nsc, 256, 0, stream>>>(z, Wm, W1, W2, esrc, edst, ew,
                                                     bhist, brun, Ab, Wt, tmp,
                                                     N, Mp, E, bz8, bw, nbk);
    sort_gemmP<<<nbk + nP + 1, 256, 0, stream>>>(tmp, bhist, offsets, s_ew,
                                                 N, E, nbk, Ab, Wt, Pb, Mp, nP,
                                                 Wm, b1, bm, W1f, bprime);
    aggregate_kernel<<<(Mp + 15) / 16, 256, 0, stream>>>(Pb, bm, Wm + 256 * 128,
                                                         offsets, s_ew, Ab, Wt,
                                                         N, Mp);
    gemm_HO<<<Mp / 128, 256, 0, stream>>>(Ab, W1f, bprime, Wt + 65536, b2, out, N);
}

// Round 11
// 207.851 us; speedup vs baseline: 3.9932x; 3.9932x over previous
//
#include <hip/hip_runtime.h>
#include <hip/hip_bf16.h>

#define HID 128

typedef short bf16x8 __attribute__((ext_vector_type(8)));
typedef float f32x4  __attribute__((ext_vector_type(4)));
typedef unsigned short u16;
typedef unsigned long long u64;

__device__ __forceinline__ u16 f2bf(float f) {
    __hip_bfloat16 h = __float2bfloat16(f);
    return *reinterpret_cast<u16*>(&h);
}
__device__ __forceinline__ float bf2f(u16 x) {
    unsigned u = ((unsigned)x) << 16;
    return __uint_as_float(u);
}
// record: dst(17b)<<31 | src(16b)<<15 | wq(15b); low 31 bits = final s_ew record
__device__ __forceinline__ u64 pack_rec(int dst, int src, float w) {
    int wq = (int)fmaf(w, 32768.f, 0.5f);
    wq = wq > 32767 ? 32767 : wq;
    return ((u64)(unsigned)dst << 31) | ((unsigned)src << 15) | (unsigned)wq;
}

// Wt layout (u16): [0,32768) Wds^T (256 rows x 128k: Wd^T then Ws^T)
//                  [32768,65536) W1^T (128 rows x 256k)
//                  [65536,81920) W2^T (128 rows x 128k)
// W1f (u16): folded W1^T rows n x 256k: k<128 = (W1a + Wd@W1b)^T, k>=128 = W1b^T.
// bprime (f32): b1 + bm@W1b.

// ---------- K1: coarse histogram only (fast, unblocks scatter) ----------
__global__ __launch_bounds__(256)
void hist_kernel(const int* __restrict__ edst, int* __restrict__ bhist,
                 int E, int nbk)
{
    __shared__ int lh[256];
    const int b = blockIdx.x;
    const int t = threadIdx.x;
    lh[t] = 0;
    __syncthreads();
    const int e0 = b * 4096;
    const int eend = min(e0 + 4096, E);
    for (int e = e0 + t; e < eend; e += 256)
        atomicAdd(&lh[edst[e] >> 8], 1);
    __syncthreads();
    if (t < nbk && lh[t] > 0) atomicAdd(&bhist[t], lh[t]);
}

// ---------- K2: z-cast (8/thread) || weight transpose/cast || bucket scatter ----------
__global__ __launch_bounds__(256)
void cast_scatter(const float* __restrict__ z, const float* __restrict__ Wm,
                  const float* __restrict__ W1, const float* __restrict__ W2,
                  const int* __restrict__ esrc, const int* __restrict__ edst,
                  const float* __restrict__ ew,
                  const int* __restrict__ bhist, int* __restrict__ brun,
                  u16* __restrict__ Ab, u16* __restrict__ Wt, u64* __restrict__ tmp,
                  int N, int Mp, int E, int bz, int bw, int nbk)
{
    const int b = blockIdx.x;
    const int t = threadIdx.x;
    if (b < bz) {
        // z-cast: 8 elems/thread
        const int idx8 = (b * 256 + t) * 8;
        const int row = idx8 >> 7, col = idx8 & 127;
        bf16x8 u;
        if (row < N) {
            const float4 v0 = *(const float4*)&z[(size_t)row * 128 + col];
            const float4 v1 = *(const float4*)&z[(size_t)row * 128 + col + 4];
            u[0] = (short)f2bf(v0.x); u[1] = (short)f2bf(v0.y);
            u[2] = (short)f2bf(v0.z); u[3] = (short)f2bf(v0.w);
            u[4] = (short)f2bf(v1.x); u[5] = (short)f2bf(v1.y);
            u[6] = (short)f2bf(v1.z); u[7] = (short)f2bf(v1.w);
        } else { u = bf16x8{0,0,0,0,0,0,0,0}; }
        *(bf16x8*)&Ab[(size_t)row * 256 + col] = u;
    } else if (b < bz + bw) {
        const int idx = (b - bz) * 256 + t;
        float v;
        if (idx < 32768) {
            const int nn = idx >> 7, k = idx & 127;
            v = (nn < 128) ? Wm[k * 128 + nn] : Wm[(128 + k) * 128 + (nn - 128)];
        } else if (idx < 65536) {
            const int j = idx - 32768, n = j >> 8, k = j & 255;
            v = W1[k * 128 + n];
        } else {
            const int j = idx - 65536, n = j >> 7, k = j & 127;
            v = W2[k * 128 + n];
        }
        Wt[idx] = f2bf(v);
    } else {
        // ---- scatter: u64 records into bucket-major order, dense runs ----
        __shared__ int cnt[256];
        __shared__ int rbase[256];
        __shared__ int bbase[256];
        __shared__ int ps[256];
        const int e0 = (b - bz - bw) * 4096;
        const int eend = min(e0 + 4096, E);

        // parallel exclusive scan of bhist -> bbase
        const int h = (t < nbk) ? bhist[t] : 0;
        ps[t] = h;
        __syncthreads();
        for (int off = 1; off < 256; off <<= 1) {
            int add = (t >= off) ? ps[t - off] : 0;
            __syncthreads();
            ps[t] += add;
            __syncthreads();
        }
        bbase[t] = ps[t] - h;
        cnt[t] = 0;
        __syncthreads();

        if (eend - e0 == 4096) {
            int myb[16]; u64 myrec[16];
#pragma unroll
            for (int i = 0; i < 16; i++) {
                const int e = e0 + t + i * 256;
                const int d = edst[e];
                myb[i] = d >> 8;
                myrec[i] = pack_rec(d, esrc[e], ew[e]);
                atomicAdd(&cnt[myb[i]], 1);
            }
            __syncthreads();
            if (t < nbk && cnt[t] > 0) rbase[t] = bbase[t] + atomicAdd(&brun[t], cnt[t]);
            __syncthreads();
            cnt[t] = 0;
            __syncthreads();
#pragma unroll
            for (int i = 0; i < 16; i++) {
                const int r = atomicAdd(&cnt[myb[i]], 1);
                tmp[(size_t)rbase[myb[i]] + r] = myrec[i];
            }
        } else {
            for (int e = e0 + t; e < eend; e += 256)
                atomicAdd(&cnt[edst[e] >> 8], 1);
            __syncthreads();
            if (t < nbk && cnt[t] > 0) rbase[t] = bbase[t] + atomicAdd(&brun[t], cnt[t]);
            __syncthreads();
            cnt[t] = 0;
            __syncthreads();
            for (int e = e0 + t; e < eend; e += 256) {
                const int d = edst[e];
                const int bk = d >> 8;
                const int r = atomicAdd(&cnt[bk], 1);
                tmp[(size_t)rbase[bk] + r] = pack_rec(d, esrc[e], ew[e]);
            }
        }
    }
}

// ---------- K3: bucket_sort || gemm_P (zWs, 128-row tile) || W'-fold prep ----------
__global__ __launch_bounds__(256)
void sort_gemmP(const u64* __restrict__ tmp, const int* __restrict__ bhist,
                int* __restrict__ offsets, unsigned* __restrict__ s_ew,
                int N, int E, int nbk,
                const u16* __restrict__ Ab, const u16* __restrict__ Wt,
                u16* __restrict__ Pb, int Mp, int nP,
                const float* __restrict__ Wm, const float* __restrict__ b1,
                const float* __restrict__ bm,
                u16* __restrict__ W1f, float* __restrict__ bprime)
{
    const int t = threadIdx.x;

    if (blockIdx.x < (unsigned)nbk) {
        __shared__ int cnt[256];
        __shared__ int cur[256];
        __shared__ int ps[256];
        const int b = blockIdx.x;
        const int n0 = b << 8;
        const int nhi = min(256, N - n0);

        // parallel scan of bhist -> this bucket's [base, endp)
        const int h = (t < nbk) ? bhist[t] : 0;
        ps[t] = h;
        __syncthreads();
        for (int off = 1; off < 256; off <<= 1) {
            int add = (t >= off) ? ps[t - off] : 0;
            __syncthreads();
            ps[t] += add;
            __syncthreads();
        }
        const int base = (b > 0) ? ps[b - 1] : 0;
        const int endp = ps[b];
        cnt[t] = 0;
        __syncthreads();

        for (int r = base + t; r < endp; r += 256)
            atomicAdd(&cnt[(int)(tmp[r] >> 31) - n0], 1);
        __syncthreads();

        const int v = cnt[t];
        ps[t] = v;
        __syncthreads();
        for (int off = 1; off < 256; off <<= 1) {
            int add = (t >= off) ? ps[t - off] : 0;
            __syncthreads();
            ps[t] += add;
            __syncthreads();
        }
        cur[t] = base + ps[t] - v;
        __syncthreads();

        if (t < nhi) offsets[n0 + t] = cur[t];
        if (t == 0 && n0 + nhi == N) offsets[N] = E;

        for (int r = base + t; r < endp; r += 256) {
            const u64 rec = tmp[r];
            const int local = (int)(rec >> 31) - n0;
            const int pos = atomicAdd(&cur[local], 1);
            s_ew[pos] = (unsigned)(rec & 0x7FFFFFFFu);
        }
    } else if (blockIdx.x < (unsigned)(nbk + nP)) {
        // ---- gemm_P: Pb = z @ Ws (128 rows x 128 cols/block), A via LDS.
        // 4 waves in 2x2 grid, each 64x64 output: 16 MFMA per 8 loads per K-step.
        __shared__ u16 As[128 * 136];
        const int row0 = (blockIdx.x - nbk) * 128;
        const int wv = t >> 6, lane = t & 63;
        const int wy = wv & 1, wx = wv >> 1;
        const int q = lane >> 4, n = lane & 15;

#pragma unroll
        for (int i = 0; i < 8; i++) {
            const int chunk = i * 256 + t;
            const int row = chunk >> 4;
            const int c8 = chunk & 15;
            *(bf16x8*)&As[row * 136 + c8 * 8] =
                *(const bf16x8*)&Ab[(size_t)(row0 + row) * 256 + c8 * 8];
        }
        __syncthreads();

        const u16* pAl = As + (wy * 64 + n) * 136 + q * 8;
        const u16* pB = Wt + (size_t)(128 + wx * 64 + n) * 128 + q * 8;

        f32x4 acc[4][4];
#pragma unroll
        for (int i = 0; i < 4; i++)
#pragma unroll
            for (int j = 0; j < 4; j++) acc[i][j] = f32x4{0.f, 0.f, 0.f, 0.f};

#pragma unroll
        for (int kk = 0; kk < 128; kk += 32) {
            bf16x8 a[4], bfr[4];
#pragma unroll
            for (int mi = 0; mi < 4; mi++)
                a[mi] = *(const bf16x8*)(pAl + mi * 16 * 136 + kk);
#pragma unroll
            for (int ni = 0; ni < 4; ni++)
                bfr[ni] = *(const bf16x8*)(pB + (size_t)ni * 16 * 128 + kk);
#pragma unroll
            for (int mi = 0; mi < 4; mi++)
#pragma unroll
                for (int ni = 0; ni < 4; ni++)
                    acc[mi][ni] = __builtin_amdgcn_mfma_f32_16x16x32_bf16(a[mi], bfr[ni], acc[mi][ni], 0, 0, 0);
        }

#pragma unroll
        for (int mi = 0; mi < 4; mi++) {
#pragma unroll
            for (int ni = 0; ni < 4; ni++) {
                const int rbase2 = row0 + wy * 64 + mi * 16 + q * 4;
                const int c = wx * 64 + ni * 16 + n;
#pragma unroll
                for (int r = 0; r < 4; r++)
                    Pb[(size_t)(rbase2 + r) * 128 + c] = f2bf(acc[mi][ni][r]);
            }
        }
    } else {
        // ---- W'-fold prep: W1f[n][k<128] = W1a^T + (Wd@W1b)^T; copy W1b^T half;
        //      bprime = b1 + bm@W1b.  One block, 4 waves, out 128x128 via MFMA.
        const u16* W1t = Wt + 32768;
        const int wv = t >> 6, lane = t & 63;
        const int q = lane >> 4, n16 = lane & 15;

        // copy W1b^T half (rows n, cols 128..255)
#pragma unroll
        for (int i = 0; i < 8; i++) {
            const int idx8 = (i * 256 + t) * 8;      // 0..16383
            const int row = idx8 >> 7, c = idx8 & 127;
            *(bf16x8*)&W1f[row * 256 + 128 + c] =
                *(const bf16x8*)&W1t[row * 256 + 128 + c];
        }

        // M[n][j] = sum_c W1b[c][n] * Wd[j][c]
        const int r0 = wv * 32;
        const u16* pA = W1t + (size_t)(r0 + n16) * 256 + 128 + q * 8;

        f32x4 acc[2][8];
#pragma unroll
        for (int i = 0; i < 2; i++)
#pragma unroll
            for (int j = 0; j < 8; j++) acc[i][j] = f32x4{0.f, 0.f, 0.f, 0.f};

#pragma unroll
        for (int kk = 0; kk < 128; kk += 32) {
            bf16x8 a0 = *(const bf16x8*)(pA + kk);
            bf16x8 a1 = *(const bf16x8*)(pA + 16 * 256 + kk);
            bf16x8 bfr[8];
#pragma unroll
            for (int ni = 0; ni < 8; ni++) {
                const float* src = &Wm[(size_t)(ni * 16 + n16) * 128 + kk + q * 8];
                const float4 v0 = *(const float4*)src;
                const float4 v1 = *(const float4*)(src + 4);
                bf16x8 bb;
                bb[0] = (short)f2bf(v0.x); bb[1] = (short)f2bf(v0.y);
                bb[2] = (short)f2bf(v0.z); bb[3] = (short)f2bf(v0.w);
                bb[4] = (short)f2bf(v1.x); bb[5] = (short)f2bf(v1.y);
                bb[6] = (short)f2bf(v1.z); bb[7] = (short)f2bf(v1.w);
                bfr[ni] = bb;
            }
#pragma unroll
            for (int ni = 0; ni < 8; ni++) {
                acc[0][ni] = __builtin_amdgcn_mfma_f32_16x16x32_bf16(a0, bfr[ni], acc[0][ni], 0, 0, 0);
                acc[1][ni] = __builtin_amdgcn_mfma_f32_16x16x32_bf16(a1, bfr[ni], acc[1][ni], 0, 0, 0);
            }
        }

#pragma unroll
        for (int mi = 0; mi < 2; mi++) {
#pragma unroll
            for (int ni = 0; ni < 8; ni++) {
                const int row = r0 + mi * 16 + q * 4;
                const int c = ni * 16 + n16;
#pragma unroll
                for (int r = 0; r < 4; r++) {
                    const int rr = row + r;
                    W1f[rr * 256 + c] =
                        f2bf(acc[mi][ni][r] + bf2f(W1t[rr * 256 + c]));
                }
            }
        }

        // bprime[n] = b1[n] + sum_c bm[c]*W1b[c][n]
        if (t < 128) {
            float s = b1[t];
            for (int c = 0; c < 128; c++)
                s = fmaf(bm[c], bf2f(W1t[t * 256 + 128 + c]), s);
            bprime[t] = s;
        }
    }
}

// ---------- per-node segmented max of (zWs[src] + ew*ww) -> Ab agg slice ----------
// GROUP-PER-NODE (16-lane group owns one node). Stores raw m (fold handles the
// zWd+bm part via W1f/bprime). deg-0 nodes store m = -(zWd+bm) so agg==0 exactly.
__global__ __launch_bounds__(256)
void aggregate_kernel(const u16* __restrict__ Pb,
                      const float* __restrict__ bm,
                      const float* __restrict__ ww,
                      const int* __restrict__ offsets,
                      const unsigned* __restrict__ s_ew,
                      u16* __restrict__ Ab,
                      const u16* __restrict__ WdT,
                      int N, int Mp)
{
    const int t = threadIdx.x;
    const int lane = t & 63;
    const int c0 = (lane & 15) * 8;     // 8 contiguous cols per lane
    const int nd = blockIdx.x * 16 + ((t >> 6) << 2) + (lane >> 4);
    if (nd >= Mp) return;

    u16* dst = &Ab[(size_t)nd * 256 + 128 + c0];

    if (nd >= N) {
        bf16x8 zv = {0, 0, 0, 0, 0, 0, 0, 0};
        *(bf16x8*)dst = zv;
        return;
    }

    const int start = offsets[nd];
    const int end   = offsets[nd + 1];

    if (end <= start) {
        // deg-0: m = -(zWd + bm) so the folded H gets agg==0 exactly (rare path)
        float acc8[8];
#pragma unroll
        for (int j = 0; j < 8; j++) acc8[j] = 0.f;
        for (int k = 0; k < 128; k++) {
            const float zk = bf2f(Ab[(size_t)nd * 256 + k]);
#pragma unroll
            for (int j = 0; j < 8; j++)
                acc8[j] = fmaf(zk, bf2f(WdT[(size_t)(c0 + j) * 128 + k]), acc8[j]);
        }
        bf16x8 outv;
#pragma unroll
        for (int j = 0; j < 8; j++)
            outv[j] = (short)f2bf(-(acc8[j] + bm[c0 + j]));
        *(bf16x8*)dst = outv;
        return;
    }

    float wwv[8];
    {
        const float4 wa = *(const float4*)&ww[c0];
        const float4 wb = *(const float4*)&ww[c0 + 4];
        wwv[0] = wa.x; wwv[1] = wa.y; wwv[2] = wa.z; wwv[3] = wa.w;
        wwv[4] = wb.x; wwv[5] = wb.y; wwv[6] = wb.z; wwv[7] = wb.w;
    }

    const float kq = 1.f / 32768.f;
    float m[8];
#pragma unroll
    for (int j = 0; j < 8; j++) m[j] = -INFINITY;

    const int last = end - 1;
    for (int eb = start; eb < end; eb += 8) {
        unsigned u[8];
#pragma unroll
        for (int i = 0; i < 8; i++) {
            int e = eb + i; if (e > last) e = last;
            u[i] = s_ew[e];
        }
        bf16x8 p[8];
#pragma unroll
        for (int i = 0; i < 8; i++)
            p[i] = *(const bf16x8*)&Pb[(size_t)(u[i] >> 15) * 128 + c0];
#pragma unroll
        for (int i = 0; i < 8; i++) {
            const float w = (float)(u[i] & 32767u) * kq;
#pragma unroll
            for (int j = 0; j < 8; j++)
                m[j] = fmaxf(m[j], fmaf(w, wwv[j], bf2f((u16)p[i][j])));
        }
    }

    bf16x8 outv;
#pragma unroll
    for (int j = 0; j < 8; j++)
        outv[j] = (short)f2bf(m[j]);
    *(bf16x8*)dst = outv;
}

// ---------- fused: H = relu([z|m]@W1f+b') (K=256) -> LDS -> out = H@W2+b2 ----------
// 128-row blocks: each of 4 waves owns a 64x64 output tile (acc[4][4]),
// 16 MFMA per 8 fragment loads per K-step.
__global__ __launch_bounds__(256)
void gemm_HO(const u16* __restrict__ Ab, const u16* __restrict__ W1t,
             const float* __restrict__ b1, const u16* __restrict__ W2t,
             const float* __restrict__ b2, float* __restrict__ out, int Mstore)
{
    __shared__ u16 smem[128 * 264];   // 67.5 KB: As 128x(256+8); phase2 reuses as Hs 128x136

    const int row0 = blockIdx.x * 128;
    const int tid = threadIdx.x;
    const int wv = tid >> 6, lane = tid & 63;
    const int wy = wv & 1, wx = wv >> 1;
    const int q = lane >> 4, n = lane & 15;

    // stage A-tile: 128 rows x 256 cols bf16
#pragma unroll
    for (int i = 0; i < 16; i++) {
        const int chunk = i * 256 + tid;
        const int row = chunk >> 5;
        const int c8 = chunk & 31;
        *(bf16x8*)&smem[row * 264 + c8 * 8] =
            *(const bf16x8*)&Ab[(size_t)(row0 + row) * 256 + c8 * 8];
    }
    __syncthreads();

    f32x4 acc[4][4];

    // ---- phase 1: H tile (128 x 128), K=256, A from LDS ----
    {
        const u16* pAl = smem + (wy * 64 + n) * 264 + q * 8;
        const u16* pB = W1t + (size_t)(wx * 64 + n) * 256 + q * 8;

#pragma unroll
        for (int i = 0; i < 4; i++)
#pragma unroll
            for (int j = 0; j < 4; j++) acc[i][j] = f32x4{0.f, 0.f, 0.f, 0.f};

#pragma unroll
        for (int kk = 0; kk < 256; kk += 32) {
            bf16x8 a[4], bfr[4];
#pragma unroll
            for (int mi = 0; mi < 4; mi++)
                a[mi] = *(const bf16x8*)(pAl + mi * 16 * 264 + kk);
#pragma unroll
            for (int ni = 0; ni < 4; ni++)
                bfr[ni] = *(const bf16x8*)(pB + (size_t)ni * 16 * 256 + kk);
#pragma unroll
            for (int mi = 0; mi < 4; mi++)
#pragma unroll
                for (int ni = 0; ni < 4; ni++)
                    acc[mi][ni] = __builtin_amdgcn_mfma_f32_16x16x32_bf16(a[mi], bfr[ni], acc[mi][ni], 0, 0, 0);
        }
    }
    __syncthreads();

#pragma unroll
    for (int mi = 0; mi < 4; mi++) {
#pragma unroll
        for (int ni = 0; ni < 4; ni++) {
            const int rl = wy * 64 + mi * 16 + q * 4;
            const int c = wx * 64 + ni * 16 + n;
#pragma unroll
            for (int r = 0; r < 4; r++) {
                float v = acc[mi][ni][r] + b1[c];
                smem[(rl + r) * 136 + c] = f2bf(fmaxf(v, 0.f));
            }
        }
    }
    __syncthreads();

    // ---- phase 2: out tile (128 x 128) = Hs @ W2t + b2, K=128 ----
    {
        const u16* pB = W2t + (size_t)(wx * 64 + n) * 128 + q * 8;
        const u16* pHl = smem + (wy * 64 + n) * 136 + q * 8;

#pragma unroll
        for (int i = 0; i < 4; i++)
#pragma unroll
            for (int j = 0; j < 4; j++) acc[i][j] = f32x4{0.f, 0.f, 0.f, 0.f};

#pragma unroll
        for (int kk = 0; kk < 128; kk += 32) {
            bf16x8 a[4], bfr[4];
#pragma unroll
            for (int mi = 0; mi < 4; mi++)
                a[mi] = *(const bf16x8*)(pHl + mi * 16 * 136 + kk);
#pragma unroll
            for (int ni = 0; ni < 4; ni++)
                bfr[ni] = *(const bf16x8*)(pB + (size_t)ni * 16 * 128 + kk);
#pragma unroll
            for (int mi = 0; mi < 4; mi++)
#pragma unroll
                for (int ni = 0; ni < 4; ni++)
                    acc[mi][ni] = __builtin_amdgcn_mfma_f32_16x16x32_bf16(a[mi], bfr[ni], acc[mi][ni], 0, 0, 0);
        }

#pragma unroll
        for (int mi = 0; mi < 4; mi++) {
#pragma unroll
            for (int ni = 0; ni < 4; ni++) {
                const int rbase = row0 + wy * 64 + mi * 16 + q * 4;
                const int c = wx * 64 + ni * 16 + n;
#pragma unroll
                for (int r = 0; r < 4; r++) {
                    const int rr = rbase + r;
                    if (rr >= Mstore) continue;
                    out[(size_t)rr * 128 + c] = acc[mi][ni][r] + b2[c];
                }
            }
        }
    }
}

extern "C" void kernel_launch(void* const* d_in, const int* in_sizes, int n_in,
                              void* d_out, int out_size, void* d_ws, size_t ws_size,
                              hipStream_t stream) {
    const float* z    = (const float*)d_in[0];
    const float* ew   = (const float*)d_in[1];
    const int*   esrc = (const int*)d_in[2];
    const int*   edst = (const int*)d_in[3];
    const float* Wm   = (const float*)d_in[4];
    const float* bm   = (const float*)d_in[5];
    const float* W1   = (const float*)d_in[6];
    const float* b1   = (const float*)d_in[7];
    const float* W2   = (const float*)d_in[8];
    const float* b2   = (const float*)d_in[9];
    float* out = (float*)d_out;

    const int N  = in_sizes[0] / HID;          // 50000
    const int E  = in_sizes[1];                // 800000
    const int Mp = ((N + 127) / 128) * 128;    // 50048 (multiple of 128)
    const int nbk = (N + 255) / 256;           // 196 buckets (256 nodes each)
    const int nP  = Mp / 128;                  // gemm_P blocks (128-row tiles)

    // workspace layout
    char* w = (char*)d_ws;
    u16*  Ab      = (u16*)w;      w += (size_t)Mp * 256 * 2;   // [zb | m]
    u16*  Pb      = (u16*)w;      w += (size_t)Mp * 128 * 2;   // zWs only
    u16*  Wt      = (u16*)w;      w += (size_t)81920 * 2;
    u16*  W1f     = (u16*)w;      w += (size_t)32768 * 2;      // folded W1^T
    float* bprime = (float*)w;    w += 128 * 4;
    int*  offsets = (int*)w;      w += (size_t)(N + 64) * 4;
    int*  bhist   = (int*)w;      w += 256 * 4;
    int*  brun    = (int*)w;      w += 256 * 4;
    unsigned* s_ew = (unsigned*)w; w += (size_t)E * 4;
    u64*  tmp     = (u64*)w;      w += (size_t)E * 8;

    const int bz8 = (Mp * 16 + 255) / 256;     // z-cast blocks (8 elems/thread)
    const int bw  = (81920 + 255) / 256;       // weight blocks
    const int nsc = (E + 4095) / 4096;         // scatter / hist blocks

    hipMemsetAsync(bhist, 0, 512 * sizeof(int), stream);   // bhist + brun
    // K1: histogram only - unblocks scatter fast
    hist_kernel<<<nsc, 256, 0, stream>>>(edst, bhist, E, nbk);
    // K2: z-cast || weight-cast || scatter
    cast_scatter<<<bz8 + bw + nsc, 256, 0, stream>>>(z, Wm, W1, W2, esrc, edst, ew,
                                                     bhist, brun, Ab, Wt, tmp,
                                                     N, Mp, E, bz8, bw, nbk);
    // K3: bucket_sort || gemm_P (128-row tile) || W'-fold prep
    sort_gemmP<<<nbk + nP + 1, 256, 0, stream>>>(tmp, bhist, offsets, s_ew,
                                                 N, E, nbk, Ab, Wt, Pb, Mp, nP,
                                                 Wm, b1, bm, W1f, bprime);
    aggregate_kernel<<<(Mp + 15) / 16, 256, 0, stream>>>(Pb, bm, Wm + 256 * 128,
                                                         offsets, s_ew, Ab, Wt,
                                                         N, Mp);
    gemm_HO<<<Mp / 128, 256, 0, stream>>>(Ab, W1f, bprime, Wt + 65536, b2, out, N);
}

// Round 12
// 198.510 us; speedup vs baseline: 4.1811x; 1.0471x over previous
//
#include <hip/hip_runtime.h>
#include <hip/hip_bf16.h>

#define HID 128

typedef short bf16x8 __attribute__((ext_vector_type(8)));
typedef float f32x4  __attribute__((ext_vector_type(4)));
typedef unsigned short u16;
typedef unsigned long long u64;

__device__ __forceinline__ u16 f2bf(float f) {
    __hip_bfloat16 h = __float2bfloat16(f);
    return *reinterpret_cast<u16*>(&h);
}
__device__ __forceinline__ float bf2f(u16 x) {
    unsigned u = ((unsigned)x) << 16;
    return __uint_as_float(u);
}
// record: dst(17b)<<31 | src(16b)<<15 | wq(15b); low 31 bits = final s_ew record
__device__ __forceinline__ u64 pack_rec(int dst, int src, float w) {
    int wq = (int)fmaf(w, 32768.f, 0.5f);
    wq = wq > 32767 ? 32767 : wq;
    return ((u64)(unsigned)dst << 31) | ((unsigned)src << 15) | (unsigned)wq;
}

// Wt layout (u16): [0,32768) Wds^T (256 rows x 128k: Wd^T then Ws^T)
//                  [32768,65536) W1^T (128 rows x 256k)
//                  [65536,81920) W2^T (128 rows x 128k)
// W1f (u16): folded W1^T rows n x 256k: k<128 = (W1a + Wd@W1b)^T, k>=128 = W1b^T.
// bprime (f32): b1 + bm@W1b.

// ---------- K1: coarse histogram only (fast, unblocks scatter) ----------
__global__ __launch_bounds__(256)
void hist_kernel(const int* __restrict__ edst, int* __restrict__ bhist,
                 int E, int nbk)
{
    __shared__ int lh[256];
    const int b = blockIdx.x;
    const int t = threadIdx.x;
    lh[t] = 0;
    __syncthreads();
    const int e0 = b * 4096;
    const int eend = min(e0 + 4096, E);
    for (int e = e0 + t; e < eend; e += 256)
        atomicAdd(&lh[edst[e] >> 8], 1);
    __syncthreads();
    if (t < nbk && lh[t] > 0) atomicAdd(&bhist[t], lh[t]);
}

// ---------- K2: z-cast (8/thread) || weight transpose/cast || bucket scatter ----------
__global__ __launch_bounds__(256)
void cast_scatter(const float* __restrict__ z, const float* __restrict__ Wm,
                  const float* __restrict__ W1, const float* __restrict__ W2,
                  const int* __restrict__ esrc, const int* __restrict__ edst,
                  const float* __restrict__ ew,
                  const int* __restrict__ bhist, int* __restrict__ brun,
                  u16* __restrict__ Ab, u16* __restrict__ Wt, u64* __restrict__ tmp,
                  int N, int Mp, int E, int bz, int bw, int nbk)
{
    const int b = blockIdx.x;
    const int t = threadIdx.x;
    if (b < bz) {
        // z-cast: 8 elems/thread
        const int idx8 = (b * 256 + t) * 8;
        const int row = idx8 >> 7, col = idx8 & 127;
        bf16x8 u;
        if (row < N) {
            const float4 v0 = *(const float4*)&z[(size_t)row * 128 + col];
            const float4 v1 = *(const float4*)&z[(size_t)row * 128 + col + 4];
            u[0] = (short)f2bf(v0.x); u[1] = (short)f2bf(v0.y);
            u[2] = (short)f2bf(v0.z); u[3] = (short)f2bf(v0.w);
            u[4] = (short)f2bf(v1.x); u[5] = (short)f2bf(v1.y);
            u[6] = (short)f2bf(v1.z); u[7] = (short)f2bf(v1.w);
        } else { u = bf16x8{0,0,0,0,0,0,0,0}; }
        *(bf16x8*)&Ab[(size_t)row * 256 + col] = u;
    } else if (b < bz + bw) {
        const int idx = (b - bz) * 256 + t;
        float v;
        if (idx < 32768) {
            const int nn = idx >> 7, k = idx & 127;
            v = (nn < 128) ? Wm[k * 128 + nn] : Wm[(128 + k) * 128 + (nn - 128)];
        } else if (idx < 65536) {
            const int j = idx - 32768, n = j >> 8, k = j & 255;
            v = W1[k * 128 + n];
        } else {
            const int j = idx - 65536, n = j >> 7, k = j & 127;
            v = W2[k * 128 + n];
        }
        Wt[idx] = f2bf(v);
    } else {
        // ---- scatter: u64 records into bucket-major order, dense runs ----
        __shared__ int cnt[256];
        __shared__ int rbase[256];
        __shared__ int bbase[256];
        __shared__ int ps[256];
        const int e0 = (b - bz - bw) * 4096;
        const int eend = min(e0 + 4096, E);

        // parallel exclusive scan of bhist -> bbase
        const int h = (t < nbk) ? bhist[t] : 0;
        ps[t] = h;
        __syncthreads();
        for (int off = 1; off < 256; off <<= 1) {
            int add = (t >= off) ? ps[t - off] : 0;
            __syncthreads();
            ps[t] += add;
            __syncthreads();
        }
        bbase[t] = ps[t] - h;
        cnt[t] = 0;
        __syncthreads();

        if (eend - e0 == 4096) {
            int myb[16]; u64 myrec[16];
#pragma unroll
            for (int i = 0; i < 16; i++) {
                const int e = e0 + t + i * 256;
                const int d = edst[e];
                myb[i] = d >> 8;
                myrec[i] = pack_rec(d, esrc[e], ew[e]);
                atomicAdd(&cnt[myb[i]], 1);
            }
            __syncthreads();
            if (t < nbk && cnt[t] > 0) rbase[t] = bbase[t] + atomicAdd(&brun[t], cnt[t]);
            __syncthreads();
            cnt[t] = 0;
            __syncthreads();
#pragma unroll
            for (int i = 0; i < 16; i++) {
                const int r = atomicAdd(&cnt[myb[i]], 1);
                tmp[(size_t)rbase[myb[i]] + r] = myrec[i];
            }
        } else {
            for (int e = e0 + t; e < eend; e += 256)
                atomicAdd(&cnt[edst[e] >> 8], 1);
            __syncthreads();
            if (t < nbk && cnt[t] > 0) rbase[t] = bbase[t] + atomicAdd(&brun[t], cnt[t]);
            __syncthreads();
            cnt[t] = 0;
            __syncthreads();
            for (int e = e0 + t; e < eend; e += 256) {
                const int d = edst[e];
                const int bk = d >> 8;
                const int r = atomicAdd(&cnt[bk], 1);
                tmp[(size_t)rbase[bk] + r] = pack_rec(d, esrc[e], ew[e]);
            }
        }
    }
}

// ---------- K3: bucket_sort || gemm_P (zWs only, 64x128) || W'-fold prep ----------
__global__ __launch_bounds__(256)
void sort_gemmP(const u64* __restrict__ tmp, const int* __restrict__ bhist,
                int* __restrict__ offsets, unsigned* __restrict__ s_ew,
                int N, int E, int nbk,
                const u16* __restrict__ Ab, const u16* __restrict__ Wt,
                u16* __restrict__ Pb, int Mp, int nP,
                const float* __restrict__ Wm, const float* __restrict__ b1,
                const float* __restrict__ bm,
                u16* __restrict__ W1f, float* __restrict__ bprime)
{
    const int t = threadIdx.x;

    if (blockIdx.x < (unsigned)nbk) {
        __shared__ int cnt[256];
        __shared__ int cur[256];
        __shared__ int ps[256];
        const int b = blockIdx.x;
        const int n0 = b << 8;
        const int nhi = min(256, N - n0);

        // parallel scan of bhist -> this bucket's [base, endp)
        const int h = (t < nbk) ? bhist[t] : 0;
        ps[t] = h;
        __syncthreads();
        for (int off = 1; off < 256; off <<= 1) {
            int add = (t >= off) ? ps[t - off] : 0;
            __syncthreads();
            ps[t] += add;
            __syncthreads();
        }
        const int base = (b > 0) ? ps[b - 1] : 0;
        const int endp = ps[b];
        cnt[t] = 0;
        __syncthreads();

        for (int r = base + t; r < endp; r += 256)
            atomicAdd(&cnt[(int)(tmp[r] >> 31) - n0], 1);
        __syncthreads();

        const int v = cnt[t];
        ps[t] = v;
        __syncthreads();
        for (int off = 1; off < 256; off <<= 1) {
            int add = (t >= off) ? ps[t - off] : 0;
            __syncthreads();
            ps[t] += add;
            __syncthreads();
        }
        cur[t] = base + ps[t] - v;
        __syncthreads();

        if (t < nhi) offsets[n0 + t] = cur[t];
        if (t == 0 && n0 + nhi == N) offsets[N] = E;

        for (int r = base + t; r < endp; r += 256) {
            const u64 rec = tmp[r];
            const int local = (int)(rec >> 31) - n0;
            const int pos = atomicAdd(&cur[local], 1);
            s_ew[pos] = (unsigned)(rec & 0x7FFFFFFFu);
        }
    } else if (blockIdx.x < (unsigned)(nbk + nP)) {
        // ---- gemm_P: Pb = z @ Ws only (64 rows x 128 cols), A via LDS ----
        __shared__ u16 As[64 * 136];
        const int row0 = (blockIdx.x - nbk) * 64;
        const int wv = t >> 6, lane = t & 63;
        const int wy = wv & 1, wx = wv >> 1;
        const int q = lane >> 4, n = lane & 15;

#pragma unroll
        for (int i = 0; i < 4; i++) {
            const int chunk = i * 256 + t;
            const int row = chunk >> 4;
            const int c8 = chunk & 15;
            *(bf16x8*)&As[row * 136 + c8 * 8] =
                *(const bf16x8*)&Ab[(size_t)(row0 + row) * 256 + c8 * 8];
        }
        __syncthreads();

        const u16* pAl = As + (wy * 32 + n) * 136 + q * 8;
        const u16* pB = Wt + (size_t)(128 + wx * 64 + n) * 128 + q * 8;

        f32x4 acc[2][4];
#pragma unroll
        for (int i = 0; i < 2; i++)
#pragma unroll
            for (int j = 0; j < 4; j++) acc[i][j] = f32x4{0.f, 0.f, 0.f, 0.f};

#pragma unroll
        for (int kk = 0; kk < 128; kk += 32) {
            bf16x8 a0 = *(const bf16x8*)(pAl + kk);
            bf16x8 a1 = *(const bf16x8*)(pAl + 16 * 136 + kk);
            bf16x8 bfr[4];
#pragma unroll
            for (int ni = 0; ni < 4; ni++)
                bfr[ni] = *(const bf16x8*)(pB + (size_t)ni * 16 * 128 + kk);
#pragma unroll
            for (int ni = 0; ni < 4; ni++) {
                acc[0][ni] = __builtin_amdgcn_mfma_f32_16x16x32_bf16(a0, bfr[ni], acc[0][ni], 0, 0, 0);
                acc[1][ni] = __builtin_amdgcn_mfma_f32_16x16x32_bf16(a1, bfr[ni], acc[1][ni], 0, 0, 0);
            }
        }

#pragma unroll
        for (int mi = 0; mi < 2; mi++) {
#pragma unroll
            for (int ni = 0; ni < 4; ni++) {
                const int rbase2 = row0 + wy * 32 + mi * 16 + q * 4;
                const int c = wx * 64 + ni * 16 + n;
#pragma unroll
                for (int r = 0; r < 4; r++)
                    Pb[(size_t)(rbase2 + r) * 128 + c] = f2bf(acc[mi][ni][r]);
            }
        }
    } else {
        // ---- W'-fold prep: W1f[n][k<128] = W1a^T + (Wd@W1b)^T; copy W1b^T half;
        //      bprime = b1 + bm@W1b.  One block, 4 waves, out 128x128 via MFMA.
        const u16* W1t = Wt + 32768;
        const int wv = t >> 6, lane = t & 63;
        const int q = lane >> 4, n16 = lane & 15;

        // copy W1b^T half (rows n, cols 128..255)
#pragma unroll
        for (int i = 0; i < 8; i++) {
            const int idx8 = (i * 256 + t) * 8;      // 0..16383
            const int row = idx8 >> 7, c = idx8 & 127;
            *(bf16x8*)&W1f[row * 256 + 128 + c] =
                *(const bf16x8*)&W1t[row * 256 + 128 + c];
        }

        // M[n][j] = sum_c W1b[c][n] * Wd[j][c]
        const int r0 = wv * 32;
        const u16* pA = W1t + (size_t)(r0 + n16) * 256 + 128 + q * 8;

        f32x4 acc[2][8];
#pragma unroll
        for (int i = 0; i < 2; i++)
#pragma unroll
            for (int j = 0; j < 8; j++) acc[i][j] = f32x4{0.f, 0.f, 0.f, 0.f};

#pragma unroll
        for (int kk = 0; kk < 128; kk += 32) {
            bf16x8 a0 = *(const bf16x8*)(pA + kk);
            bf16x8 a1 = *(const bf16x8*)(pA + 16 * 256 + kk);
            bf16x8 bfr[8];
#pragma unroll
            for (int ni = 0; ni < 8; ni++) {
                const float* src = &Wm[(size_t)(ni * 16 + n16) * 128 + kk + q * 8];
                const float4 v0 = *(const float4*)src;
                const float4 v1 = *(const float4*)(src + 4);
                bf16x8 bb;
                bb[0] = (short)f2bf(v0.x); bb[1] = (short)f2bf(v0.y);
                bb[2] = (short)f2bf(v0.z); bb[3] = (short)f2bf(v0.w);
                bb[4] = (short)f2bf(v1.x); bb[5] = (short)f2bf(v1.y);
                bb[6] = (short)f2bf(v1.z); bb[7] = (short)f2bf(v1.w);
                bfr[ni] = bb;
            }
#pragma unroll
            for (int ni = 0; ni < 8; ni++) {
                acc[0][ni] = __builtin_amdgcn_mfma_f32_16x16x32_bf16(a0, bfr[ni], acc[0][ni], 0, 0, 0);
                acc[1][ni] = __builtin_amdgcn_mfma_f32_16x16x32_bf16(a1, bfr[ni], acc[1][ni], 0, 0, 0);
            }
        }

#pragma unroll
        for (int mi = 0; mi < 2; mi++) {
#pragma unroll
            for (int ni = 0; ni < 8; ni++) {
                const int row = r0 + mi * 16 + q * 4;
                const int c = ni * 16 + n16;
#pragma unroll
                for (int r = 0; r < 4; r++) {
                    const int rr = row + r;
                    W1f[rr * 256 + c] =
                        f2bf(acc[mi][ni][r] + bf2f(W1t[rr * 256 + c]));
                }
            }
        }

        // bprime[n] = b1[n] + sum_c bm[c]*W1b[c][n]
        if (t < 128) {
            float s = b1[t];
            for (int c = 0; c < 128; c++)
                s = fmaf(bm[c], bf2f(W1t[t * 256 + 128 + c]), s);
            bprime[t] = s;
        }
    }
}

// ---------- per-node segmented max of (zWs[src] + ew*ww) -> Ab agg slice ----------
// GROUP-PER-NODE (16-lane group owns one node). Stores raw m (fold handles the
// zWd+bm part via W1f/bprime). deg-0 nodes store m = -(zWd+bm) so agg==0 exactly.
__global__ __launch_bounds__(256)
void aggregate_kernel(const u16* __restrict__ Pb,
                      const float* __restrict__ bm,
                      const float* __restrict__ ww,
                      const int* __restrict__ offsets,
                      const unsigned* __restrict__ s_ew,
                      u16* __restrict__ Ab,
                      const u16* __restrict__ WdT,
                      int N, int Mp)
{
    const int t = threadIdx.x;
    const int lane = t & 63;
    const int c0 = (lane & 15) * 8;     // 8 contiguous cols per lane
    const int nd = blockIdx.x * 16 + ((t >> 6) << 2) + (lane >> 4);
    if (nd >= Mp) return;

    u16* dst = &Ab[(size_t)nd * 256 + 128 + c0];

    if (nd >= N) {
        bf16x8 zv = {0, 0, 0, 0, 0, 0, 0, 0};
        *(bf16x8*)dst = zv;
        return;
    }

    const int start = offsets[nd];
    const int end   = offsets[nd + 1];

    if (end <= start) {
        // deg-0: m = -(zWd + bm) so the folded H gets agg==0 exactly (rare path)
        float acc8[8];
#pragma unroll
        for (int j = 0; j < 8; j++) acc8[j] = 0.f;
        for (int k = 0; k < 128; k++) {
            const float zk = bf2f(Ab[(size_t)nd * 256 + k]);
#pragma unroll
            for (int j = 0; j < 8; j++)
                acc8[j] = fmaf(zk, bf2f(WdT[(size_t)(c0 + j) * 128 + k]), acc8[j]);
        }
        bf16x8 outv;
#pragma unroll
        for (int j = 0; j < 8; j++)
            outv[j] = (short)f2bf(-(acc8[j] + bm[c0 + j]));
        *(bf16x8*)dst = outv;
        return;
    }

    float wwv[8];
    {
        const float4 wa = *(const float4*)&ww[c0];
        const float4 wb = *(const float4*)&ww[c0 + 4];
        wwv[0] = wa.x; wwv[1] = wa.y; wwv[2] = wa.z; wwv[3] = wa.w;
        wwv[4] = wb.x; wwv[5] = wb.y; wwv[6] = wb.z; wwv[7] = wb.w;
    }

    const float kq = 1.f / 32768.f;
    float m[8];
#pragma unroll
    for (int j = 0; j < 8; j++) m[j] = -INFINITY;

    const int last = end - 1;
    for (int eb = start; eb < end; eb += 8) {
        unsigned u[8];
#pragma unroll
        for (int i = 0; i < 8; i++) {
            int e = eb + i; if (e > last) e = last;
            u[i] = s_ew[e];
        }
        bf16x8 p[8];
#pragma unroll
        for (int i = 0; i < 8; i++)
            p[i] = *(const bf16x8*)&Pb[(size_t)(u[i] >> 15) * 128 + c0];
#pragma unroll
        for (int i = 0; i < 8; i++) {
            const float w = (float)(u[i] & 32767u) * kq;
#pragma unroll
            for (int j = 0; j < 8; j++)
                m[j] = fmaxf(m[j], fmaf(w, wwv[j], bf2f((u16)p[i][j])));
        }
    }

    bf16x8 outv;
#pragma unroll
    for (int j = 0; j < 8; j++)
        outv[j] = (short)f2bf(m[j]);
    *(bf16x8*)dst = outv;
}

// ---------- fused: H = relu([z|m]@W1f+b') (K=256) -> LDS -> out = H@W2+b2 ----------
// 128-row blocks: each of 4 waves owns a 64x64 output tile (acc[4][4]),
// 16 MFMA per 8 fragment loads per K-step.
__global__ __launch_bounds__(256)
void gemm_HO(const u16* __restrict__ Ab, const u16* __restrict__ W1t,
             const float* __restrict__ b1, const u16* __restrict__ W2t,
             const float* __restrict__ b2, float* __restrict__ out, int Mstore)
{
    __shared__ u16 smem[128 * 264];   // 67.5 KB: As 128x(256+8); phase2 reuses as Hs 128x136

    const int row0 = blockIdx.x * 128;
    const int tid = threadIdx.x;
    const int wv = tid >> 6, lane = tid & 63;
    const int wy = wv & 1, wx = wv >> 1;
    const int q = lane >> 4, n = lane & 15;

    // stage A-tile: 128 rows x 256 cols bf16
#pragma unroll
    for (int i = 0; i < 16; i++) {
        const int chunk = i * 256 + tid;
        const int row = chunk >> 5;
        const int c8 = chunk & 31;
        *(bf16x8*)&smem[row * 264 + c8 * 8] =
            *(const bf16x8*)&Ab[(size_t)(row0 + row) * 256 + c8 * 8];
    }
    __syncthreads();

    f32x4 acc[4][4];

    // ---- phase 1: H tile (128 x 128), K=256, A from LDS ----
    {
        const u16* pAl = smem + (wy * 64 + n) * 264 + q * 8;
        const u16* pB = W1t + (size_t)(wx * 64 + n) * 256 + q * 8;

#pragma unroll
        for (int i = 0; i < 4; i++)
#pragma unroll
            for (int j = 0; j < 4; j++) acc[i][j] = f32x4{0.f, 0.f, 0.f, 0.f};

#pragma unroll
        for (int kk = 0; kk < 256; kk += 32) {
            bf16x8 a[4], bfr[4];
#pragma unroll
            for (int mi = 0; mi < 4; mi++)
                a[mi] = *(const bf16x8*)(pAl + mi * 16 * 264 + kk);
#pragma unroll
            for (int ni = 0; ni < 4; ni++)
                bfr[ni] = *(const bf16x8*)(pB + (size_t)ni * 16 * 256 + kk);
#pragma unroll
            for (int mi = 0; mi < 4; mi++)
#pragma unroll
                for (int ni = 0; ni < 4; ni++)
                    acc[mi][ni] = __builtin_amdgcn_mfma_f32_16x16x32_bf16(a[mi], bfr[ni], acc[mi][ni], 0, 0, 0);
        }
    }
    __syncthreads();

#pragma unroll
    for (int mi = 0; mi < 4; mi++) {
#pragma unroll
        for (int ni = 0; ni < 4; ni++) {
            const int rl = wy * 64 + mi * 16 + q * 4;
            const int c = wx * 64 + ni * 16 + n;
#pragma unroll
            for (int r = 0; r < 4; r++) {
                float v = acc[mi][ni][r] + b1[c];
                smem[(rl + r) * 136 + c] = f2bf(fmaxf(v, 0.f));
            }
        }
    }
    __syncthreads();

    // ---- phase 2: out tile (128 x 128) = Hs @ W2t + b2, K=128 ----
    {
        const u16* pB = W2t + (size_t)(wx * 64 + n) * 128 + q * 8;
        const u16* pHl = smem + (wy * 64 + n) * 136 + q * 8;

#pragma unroll
        for (int i = 0; i < 4; i++)
#pragma unroll
            for (int j = 0; j < 4; j++) acc[i][j] = f32x4{0.f, 0.f, 0.f, 0.f};

#pragma unroll
        for (int kk = 0; kk < 128; kk += 32) {
            bf16x8 a[4], bfr[4];
#pragma unroll
            for (int mi = 0; mi < 4; mi++)
                a[mi] = *(const bf16x8*)(pHl + mi * 16 * 136 + kk);
#pragma unroll
            for (int ni = 0; ni < 4; ni++)
                bfr[ni] = *(const bf16x8*)(pB + (size_t)ni * 16 * 128 + kk);
#pragma unroll
            for (int mi = 0; mi < 4; mi++)
#pragma unroll
                for (int ni = 0; ni < 4; ni++)
                    acc[mi][ni] = __builtin_amdgcn_mfma_f32_16x16x32_bf16(a[mi], bfr[ni], acc[mi][ni], 0, 0, 0);
        }

#pragma unroll
        for (int mi = 0; mi < 4; mi++) {
#pragma unroll
            for (int ni = 0; ni < 4; ni++) {
                const int rbase = row0 + wy * 64 + mi * 16 + q * 4;
                const int c = wx * 64 + ni * 16 + n;
#pragma unroll
                for (int r = 0; r < 4; r++) {
                    const int rr = rbase + r;
                    if (rr >= Mstore) continue;
                    out[(size_t)rr * 128 + c] = acc[mi][ni][r] + b2[c];
                }
            }
        }
    }
}

extern "C" void kernel_launch(void* const* d_in, const int* in_sizes, int n_in,
                              void* d_out, int out_size, void* d_ws, size_t ws_size,
                              hipStream_t stream) {
    const float* z    = (const float*)d_in[0];
    const float* ew   = (const float*)d_in[1];
    const int*   esrc = (const int*)d_in[2];
    const int*   edst = (const int*)d_in[3];
    const float* Wm   = (const float*)d_in[4];
    const float* bm   = (const float*)d_in[5];
    const float* W1   = (const float*)d_in[6];
    const float* b1   = (const float*)d_in[7];
    const float* W2   = (const float*)d_in[8];
    const float* b2   = (const float*)d_in[9];
    float* out = (float*)d_out;

    const int N  = in_sizes[0] / HID;          // 50000
    const int E  = in_sizes[1];                // 800000
    const int Mp = ((N + 127) / 128) * 128;    // 50048 (multiple of 128)
    const int nbk = (N + 255) / 256;           // 196 buckets (256 nodes each)
    const int nP  = Mp / 64;                   // gemm_P blocks (64-row tiles)

    // workspace layout
    char* w = (char*)d_ws;
    u16*  Ab      = (u16*)w;      w += (size_t)Mp * 256 * 2;   // [zb | m]
    u16*  Pb      = (u16*)w;      w += (size_t)Mp * 128 * 2;   // zWs only
    u16*  Wt      = (u16*)w;      w += (size_t)81920 * 2;
    u16*  W1f     = (u16*)w;      w += (size_t)32768 * 2;      // folded W1^T
    float* bprime = (float*)w;    w += 128 * 4;
    int*  offsets = (int*)w;      w += (size_t)(N + 64) * 4;
    int*  bhist   = (int*)w;      w += 256 * 4;
    int*  brun    = (int*)w;      w += 256 * 4;
    unsigned* s_ew = (unsigned*)w; w += (size_t)E * 4;
    u64*  tmp     = (u64*)w;      w += (size_t)E * 8;

    const int bz8 = (Mp * 16 + 255) / 256;     // z-cast blocks (8 elems/thread)
    const int bw  = (81920 + 255) / 256;       // weight blocks
    const int nsc = (E + 4095) / 4096;         // scatter / hist blocks

    hipMemsetAsync(bhist, 0, 512 * sizeof(int), stream);   // bhist + brun
    // K1: histogram only - unblocks scatter fast
    hist_kernel<<<nsc, 256, 0, stream>>>(edst, bhist, E, nbk);
    // K2: z-cast || weight-cast || scatter
    cast_scatter<<<bz8 + bw + nsc, 256, 0, stream>>>(z, Wm, W1, W2, esrc, edst, ew,
                                                     bhist, brun, Ab, Wt, tmp,
                                                     N, Mp, E, bz8, bw, nbk);
    // K3: bucket_sort || gemm_P (64-row tile keeps sort occupancy high) || W'-fold
    sort_gemmP<<<nbk + nP + 1, 256, 0, stream>>>(tmp, bhist, offsets, s_ew,
                                                 N, E, nbk, Ab, Wt, Pb, Mp, nP,
                                                 Wm, b1, bm, W1f, bprime);
    aggregate_kernel<<<(Mp + 15) / 16, 256, 0, stream>>>(Pb, bm, Wm + 256 * 128,
                                                         offsets, s_ew, Ab, Wt,
                                                         N, Mp);
    gemm_HO<<<Mp / 128, 256, 0, stream>>>(Ab, W1f, bprime, Wt + 65536, b2, out, N);
}